// Round 15
// baseline (1400.773 us; speedup 1.0000x reference)
//
#include <hip/hip_runtime.h>
#include <cstdint>
#include <cstddef>

// TransformerXL forward (B=4,N=1024,D=1024,H=16,DH=64,DEPTH=4, GEGLU FI=2730)
// R15: base = R14 (best, 1338us). (1) gm sigmoid GEMM fused into qkv
//      (wqkv extended to 3328 rows; epilogue splits qkv bf16 / gm sigmoid f32);
//      (2) gemm_nt256 intra-tile phase barriers dropped (only tile-end
//      vmcnt(0)+barrier remains; race-free: reads from buf p, stages to p^1).

#define DEV_INLINE __device__ __forceinline__

typedef short bf16x8 __attribute__((ext_vector_type(8)));
typedef float f32x4 __attribute__((ext_vector_type(4)));

constexpr int Bsz = 4, Nseq = 1024, Dm = 1024, Hh = 16, DH = 64, NDEPTH = 4;
constexpr int FI = 2730;        // GEGLU inner dim
constexpr int FI_PAD = 2752;    // u cols padded to /64 (zero-filled)
constexpr int FI_TILE = 2816;   // per-half weight rows padded to /128
constexpr int WIDE = 2 * FI_TILE;  // 5632: 16-row groups [16a | 16g | ...]
constexpr int NQKV = 3328;      // 3072 qkv + 32 gate/mix + 224 zero
constexpr int ROWS = Bsz * Nseq; // 4096
constexpr float EPSR = 1.1920929e-07f;

DEV_INLINE float bf2f(unsigned short u) {
  unsigned int x = ((unsigned int)u) << 16;
  float f; __builtin_memcpy(&f, &x, 4); return f;
}
DEV_INLINE unsigned short f2bf(float f) {
  unsigned int x; __builtin_memcpy(&x, &f, 4);
  unsigned int r = x + 0x7fffu + ((x >> 16) & 1u);  // RNE
  return (unsigned short)(r >> 16);
}

using gptr_t = const __attribute__((address_space(1))) void*;
using lptr_t = __attribute__((address_space(3))) void*;
DEV_INLINE void gl_lds16(const void* g, void* l) {
  __builtin_amdgcn_global_load_lds((gptr_t)g, (lptr_t)l, 16, 0, 0);
}
DEV_INLINE void fence_mem() { asm volatile("" ::: "memory"); }

// ---------------- weight fp32 -> bf16 (vectorized, with zero padding) -----------
__global__ __launch_bounds__(256)
void convf2b(const float* __restrict__ src, unsigned short* __restrict__ dst,
             int src_rows, int src_cols, int dst_cols) {
  const int r = blockIdx.y;
  const int c8 = (blockIdx.x * blockDim.x + threadIdx.x) * 8;
  if (c8 >= dst_cols) return;
  alignas(16) unsigned short o[8];
  if (r < src_rows && c8 + 8 <= src_cols) {
    const float2* p = (const float2*)&src[(size_t)r * src_cols + c8];
    const float2 v0 = p[0], v1 = p[1], v2 = p[2], v3 = p[3];
    o[0] = f2bf(v0.x); o[1] = f2bf(v0.y); o[2] = f2bf(v1.x); o[3] = f2bf(v1.y);
    o[4] = f2bf(v2.x); o[5] = f2bf(v2.y); o[6] = f2bf(v3.x); o[7] = f2bf(v3.y);
  } else {
#pragma unroll
    for (int j = 0; j < 8; ++j) {
      const int c = c8 + j;
      float v = (r < src_rows && c < src_cols) ? src[(size_t)r * src_cols + c] : 0.0f;
      o[j] = f2bf(v);
    }
  }
  *(uint4*)&dst[(size_t)r * dst_cols + c8] = *(const uint4*)o;
}

// w_in 16-row-group interleave: dst rows [32t..32t+16) = a[16t..), [+16..32) = g
__global__ __launch_bounds__(128)
void convf2b_g16(const float* __restrict__ src, unsigned short* __restrict__ dst) {
  const int p = blockIdx.y;           // 0..WIDE-1
  const int c8 = threadIdx.x * 8;     // 128 thr * 8 = 1024 cols
  const int t = p >> 5, r5 = p & 31;
  const int srow = t * 16 + (r5 & 15);
  alignas(16) unsigned short o[8];
  if (srow < FI) {
    const size_t base = ((size_t)((r5 < 16) ? 0 : 1) * FI + srow) * 1024 + c8;
    const float4 v0 = *(const float4*)&src[base];
    const float4 v1 = *(const float4*)&src[base + 4];
    o[0]=f2bf(v0.x); o[1]=f2bf(v0.y); o[2]=f2bf(v0.z); o[3]=f2bf(v0.w);
    o[4]=f2bf(v1.x); o[5]=f2bf(v1.y); o[6]=f2bf(v1.z); o[7]=f2bf(v1.w);
  } else {
#pragma unroll
    for (int j = 0; j < 8; ++j) o[j] = 0;
  }
  *(uint4*)&dst[(size_t)p * 1024 + c8] = *(const uint4*)o;
}

// ---------------- rope cos/sin tables ----------------
__global__ __launch_bounds__(256)
void rope_tables(float* __restrict__ cost, float* __restrict__ sint) {
  int idx = blockIdx.x * 256 + threadIdx.x;
  if (idx >= Nseq * 32) return;
  int n = idx >> 5, p = idx & 31;
  float freq = powf(10000.0f, -(float)(2 * p) * (1.0f / 64.0f));
  float ang = (float)n * freq;
  cost[idx] = cosf(ang);
  sint[idx] = sinf(ang);
}

// ---------------- RMSNorm variants ----------------
__global__ __launch_bounds__(256)
void rms_one(const float* __restrict__ x, const float* __restrict__ w,
             unsigned short* __restrict__ out) {
  __shared__ float sred[4];
  const int row = blockIdx.x, tid = threadIdx.x;
  const float4 v = ((const float4*)(x + (size_t)row * Dm))[tid];
  float ss = v.x * v.x + v.y * v.y + v.z * v.z + v.w * v.w;
#pragma unroll
  for (int o = 32; o >= 1; o >>= 1) ss += __shfl_xor(ss, o, 64);
  if ((tid & 63) == 0) sred[tid >> 6] = ss;
  __syncthreads();
  float rs = rsqrtf((sred[0] + sred[1] + sred[2] + sred[3]) * (1.0f / Dm) + EPSR);
  const float4 wv = ((const float4*)w)[tid];
  alignas(8) unsigned short o4[4] = { f2bf(v.x * rs * wv.x), f2bf(v.y * rs * wv.y),
                                      f2bf(v.z * rs * wv.z), f2bf(v.w * rs * wv.w) };
  *(uint2*)&out[(size_t)row * Dm + tid * 4] = *(const uint2*)o4;
}

__global__ __launch_bounds__(256)
void rms_ff(const float* __restrict__ x, const float* __restrict__ w1,
            const float* __restrict__ w2, unsigned short* __restrict__ out) {
  __shared__ float sred[4];
  const int row = blockIdx.x, tid = threadIdx.x;
  const float4 v = ((const float4*)(x + (size_t)row * Dm))[tid];
  const float4 w1v = ((const float4*)w1)[tid];
  const float4 w2v = ((const float4*)w2)[tid];
  float ss = v.x * v.x + v.y * v.y + v.z * v.z + v.w * v.w;
#pragma unroll
  for (int o = 32; o >= 1; o >>= 1) ss += __shfl_xor(ss, o, 64);
  if ((tid & 63) == 0) sred[tid >> 6] = ss;
  __syncthreads();
  float rs1 = rsqrtf((sred[0] + sred[1] + sred[2] + sred[3]) * (1.0f / Dm) + EPSR);
  float t0 = v.x * rs1 * w1v.x, t1 = v.y * rs1 * w1v.y;
  float t2 = v.z * rs1 * w1v.z, t3 = v.w * rs1 * w1v.w;
  float ss2 = t0 * t0 + t1 * t1 + t2 * t2 + t3 * t3;
#pragma unroll
  for (int o = 32; o >= 1; o >>= 1) ss2 += __shfl_xor(ss2, o, 64);
  __syncthreads();
  if ((tid & 63) == 0) sred[tid >> 6] = ss2;
  __syncthreads();
  float rs2 = rsqrtf((sred[0] + sred[1] + sred[2] + sred[3]) * (1.0f / Dm) + EPSR);
  alignas(8) unsigned short o4[4] = { f2bf(t0 * rs2 * w2v.x), f2bf(t1 * rs2 * w2v.y),
                                      f2bf(t2 * rs2 * w2v.z), f2bf(t3 * rs2 * w2v.w) };
  *(uint2*)&out[(size_t)row * Dm + tid * 4] = *(const uint2*)o4;
}

__global__ __launch_bounds__(256)
void rms_final(const float* __restrict__ x, const float* __restrict__ w,
               float* __restrict__ out) {
  __shared__ float sred[4];
  const int row = blockIdx.x, tid = threadIdx.x;
  const float4 v = ((const float4*)(x + (size_t)row * Dm))[tid];
  float ss = v.x * v.x + v.y * v.y + v.z * v.z + v.w * v.w;
#pragma unroll
  for (int o = 32; o >= 1; o >>= 1) ss += __shfl_xor(ss, o, 64);
  if ((tid & 63) == 0) sred[tid >> 6] = ss;
  __syncthreads();
  float rs = rsqrtf((sred[0] + sred[1] + sred[2] + sred[3]) * (1.0f / Dm) + EPSR);
  const float4 wv = ((const float4*)w)[tid];
  float4 o;
  o.x = v.x * rs * wv.x; o.y = v.y * rs * wv.y;
  o.z = v.z * rs * wv.z; o.w = v.w * rs * wv.w;
  ((float4*)(out + (size_t)row * Dm))[tid] = o;
}

// ---------------- 128x128 NT GEMM (R9 schedule) ----------------
// MODE: 2=f32 residual(+bias)
template <int MODE>
__global__ __launch_bounds__(256)
void gemm_nt(const unsigned short* __restrict__ A,
             const unsigned short* __restrict__ Bw,
             void* __restrict__ Cout,
             const float* __restrict__ bias,
             const float* __restrict__ resid,
             int K, int ldc, int n_store) {
  __shared__ unsigned short As[2][128 * 64];
  __shared__ unsigned short Bs[2][128 * 64];
  const int tid = threadIdx.x;
  const int m0 = blockIdx.x * 128;
  const int n0 = blockIdx.y * 128;
  const int w = tid >> 6, l = tid & 63;
  const int wm = (w >> 1) * 64, wn = (w & 1) * 64;
  const int lr = l & 15, lg = l >> 4;
  const int lsub = l & 7, lrow8 = l >> 3;
  const int colsw = (lsub ^ lrow8) << 3;
  const unsigned short* gA = &A[(size_t)(m0 + w * 8 + lrow8) * K + colsw];
  const unsigned short* gB = &Bw[(size_t)(n0 + w * 8 + lrow8) * K + colsw];
  const size_t rstep = (size_t)32 * K;
  f32x4 acc[4][4] = {};

  auto stage = [&](int buf, int kt) {
    const int o = kt * 64;
#pragma unroll
    for (int i = 0; i < 4; ++i) {
      gl_lds16(gA + i * rstep + o, &As[buf][i * 2048 + w * 512]);
      gl_lds16(gB + i * rstep + o, &Bs[buf][i * 2048 + w * 512]);
    }
  };
  auto compute = [&](int buf) {
    bf16x8 af[2][4], bfr[2][4];
#pragma unroll
    for (int ks = 0; ks < 2; ++ks) {
      const int slot = (ks * 4 + lg) ^ (lr & 7);
#pragma unroll
      for (int fj = 0; fj < 4; ++fj)
        bfr[ks][fj] = *(const bf16x8*)&Bs[buf][(wn + fj * 16 + lr) * 64 + slot * 8];
#pragma unroll
      for (int fi = 0; fi < 4; ++fi)
        af[ks][fi] = *(const bf16x8*)&As[buf][(wm + fi * 16 + lr) * 64 + slot * 8];
    }
    __builtin_amdgcn_s_setprio(1);
#pragma unroll
    for (int ks = 0; ks < 2; ++ks)
#pragma unroll
      for (int fi = 0; fi < 4; ++fi)
#pragma unroll
        for (int fj = 0; fj < 4; ++fj)
          acc[fi][fj] = __builtin_amdgcn_mfma_f32_16x16x32_bf16(af[ks][fi], bfr[ks][fj], acc[fi][fj], 0, 0, 0);
    __builtin_amdgcn_s_setprio(0);
  };

  const int nk = K >> 6;
  stage(0, 0);
  asm volatile("s_waitcnt vmcnt(0)" ::: "memory");
  __builtin_amdgcn_s_barrier();
  fence_mem();
  int cur = 0;
#pragma unroll 1
  for (int kt = 0; kt < nk; ++kt) {
    const bool more = (kt + 1 < nk);
    if (more) stage(cur ^ 1, kt + 1);
    compute(cur);
    if (more) {
      asm volatile("s_waitcnt vmcnt(0)" ::: "memory");
      __builtin_amdgcn_s_barrier();
      fence_mem();
    }
    cur ^= 1;
  }

#pragma unroll
  for (int fi = 0; fi < 4; ++fi) {
    const int rowb = m0 + wm + fi * 16 + lg * 4;
#pragma unroll
    for (int fj = 0; fj < 4; ++fj) {
      const int col = n0 + wn + fj * 16 + lr;
#pragma unroll
      for (int r = 0; r < 4; ++r) {
        const float val = acc[fi][fj][r];
        const int rr = rowb + r;
        const float bv = bias ? bias[col] : 0.0f;
        ((float*)Cout)[(size_t)rr * ldc + col] =
            resid[(size_t)rr * ldc + col] + val + bv;
      }
    }
  }
}

// ---------------- 256x256 NT GEMM: 512 thr, 8 waves (2Mx4N), BK=64 ----------------
// 4 stage-parts per K-tile, NO intra-tile barriers (reads from buf p, stages
// to p^1; tile-end vmcnt(0)+barrier only). XCD swizzle.
// MODE: 3=grouped GEGLU, 4=qkv+gm (cols<3072 bf16, 3072..3103 sigmoid->gm f32)
template <int MODE>
__global__ __launch_bounds__(512, 2)
void gemm_nt256(const unsigned short* __restrict__ A,
                const unsigned short* __restrict__ Bw,
                void* __restrict__ Cout,
                const float* __restrict__ bias,
                int K, int ldc, int nm, int nn) {
  __shared__ unsigned short As[2][256 * 64];
  __shared__ unsigned short Bs[2][256 * 64];
  const int tid = threadIdx.x;
  const int nwg = nm * nn;
  const int qq = nwg >> 3;
  const int xcd = blockIdx.x & 7, orig = blockIdx.x >> 3;
  const int wgid = xcd * qq + orig;
  const int m0 = (wgid % nm) * 256;
  const int n0 = (wgid / nm) * 256;
  const int w = tid >> 6, l = tid & 63;
  const int wm = (w >> 2) * 128, wn = (w & 3) * 64;
  const int lr = l & 15, lg = l >> 4;
  const int lsub = l & 7, lrow8 = l >> 3;
  const int colsw = (lsub ^ lrow8) << 3;
  const unsigned short* gA = &A[(size_t)(m0 + w * 8 + lrow8) * K + colsw];
  const unsigned short* gB = &Bw[(size_t)(n0 + w * 8 + lrow8) * K + colsw];
  const size_t rstep = (size_t)64 * K;
  f32x4 acc[8][4] = {};

  // part: 0 = A rows 0-127, 1 = A rows 128-255, 2 = B rows 0-127, 3 = B hi
  auto stage_part = [&](int buf, int kt, int part) {
    const int o = kt * 64;
    const int i0 = (part & 1) * 2;
    if (part < 2) {
      gl_lds16(gA + (size_t)i0 * rstep + o,       &As[buf][i0 * 4096 + w * 512]);
      gl_lds16(gA + (size_t)(i0 + 1) * rstep + o, &As[buf][(i0 + 1) * 4096 + w * 512]);
    } else {
      gl_lds16(gB + (size_t)i0 * rstep + o,       &Bs[buf][i0 * 4096 + w * 512]);
      gl_lds16(gB + (size_t)(i0 + 1) * rstep + o, &Bs[buf][(i0 + 1) * 4096 + w * 512]);
    }
  };

  const int nk = K >> 6;
  stage_part(0, 0, 0); stage_part(0, 0, 1);
  stage_part(0, 0, 2); stage_part(0, 0, 3);
  asm volatile("s_waitcnt vmcnt(0)" ::: "memory");
  __builtin_amdgcn_s_barrier();
  fence_mem();

#pragma unroll 1
  for (int t = 0; t < nk; ++t) {
    const int p = t & 1;
    const bool more = (t + 1 < nk);
    bf16x8 bfr[4];
#pragma unroll
    for (int q = 0; q < 4; ++q) {
      const int ks = q >> 1, half = q & 1;
      const int slot = (ks * 4 + lg) ^ (lr & 7);
      if (half == 0) {
#pragma unroll
        for (int fj = 0; fj < 4; ++fj)
          bfr[fj] = *(const bf16x8*)&Bs[p][(wn + fj * 16 + lr) * 64 + slot * 8];
      }
      bf16x8 af[4];
#pragma unroll
      for (int fi = 0; fi < 4; ++fi)
        af[fi] = *(const bf16x8*)&As[p][(wm + half * 64 + fi * 16 + lr) * 64 + slot * 8];
      if (more) stage_part(p ^ 1, t + 1, q);   // one half-tile per phase
      __builtin_amdgcn_s_setprio(1);
#pragma unroll
      for (int fi = 0; fi < 4; ++fi)
#pragma unroll
        for (int fj = 0; fj < 4; ++fj)
          acc[half * 4 + fi][fj] =
              __builtin_amdgcn_mfma_f32_16x16x32_bf16(af[fi], bfr[fj], acc[half * 4 + fi][fj], 0, 0, 0);
      __builtin_amdgcn_s_setprio(0);
      // no intra-tile barrier: reads hit buf p only, stages hit p^1 only
    }
    if (more) {
      asm volatile("s_waitcnt vmcnt(0)" ::: "memory");  // tile t+1 landed
      __builtin_amdgcn_s_barrier();                     // block-wide; buf p free
      fence_mem();
    }
  }

#pragma unroll
  for (int fi = 0; fi < 8; ++fi) {
    const int rowb = m0 + wm + fi * 16 + lg * 4;
    if constexpr (MODE == 4) {
      // qkv region: cols < 3072 bf16; 3072..3103: sigmoid -> gm f32; else skip
      float* gmout = const_cast<float*>(bias);
#pragma unroll
      for (int fj = 0; fj < 4; ++fj) {
        const int col = n0 + wn + fj * 16 + lr;
#pragma unroll
        for (int r = 0; r < 4; ++r) {
          const float val = acc[fi][fj][r];
          const int rr = rowb + r;
          if (col < 3072) {
            ((unsigned short*)Cout)[(size_t)rr * 3072 + col] = f2bf(val);
          } else if (col < 3104) {
            gmout[(size_t)rr * 32 + (col - 3072)] = 1.0f / (1.0f + __expf(-val));
          }
        }
      }
    } else {  // MODE 3: cols in 16-groups [a|g]; pair (2*fjp, 2*fjp+1) in-thread
#pragma unroll
      for (int fjp = 0; fjp < 2; ++fjp) {
        const int ucol = ((n0 + wn) >> 1) + fjp * 16 + lr;
        if (ucol >= FI_PAD) continue;
        const bool live = (ucol < FI);
        const float ba = live ? bias[ucol] : 0.0f;
        const float bg = live ? bias[FI + ucol] : 0.0f;
#pragma unroll
        for (int r = 0; r < 4; ++r) {
          const float va = acc[fi][2 * fjp][r] + ba;
          const float vg = acc[fi][2 * fjp + 1][r] + bg;
          const float gel = 0.5f * vg * (1.0f + erff(vg * 0.70710678118654752f));
          ((unsigned short*)Cout)[(size_t)(rowb + r) * ldc + ucol] =
              f2bf(live ? va * gel : 0.0f);
        }
      }
    }
  }
}

// ---------------- RoPE on q,k (q also * DH^-0.5) ----------------
__global__ __launch_bounds__(256)
void rope_qk(const unsigned short* __restrict__ qkv_lin,
             const float* __restrict__ cost, const float* __restrict__ sint,
             unsigned short* __restrict__ qb, unsigned short* __restrict__ kb) {
  const int nt = blockIdx.x, bh = blockIdx.y;
  const int b = bh >> 4, h = bh & 15;
  const int tid = threadIdx.x;
  const int pi = tid & 31, r0 = tid >> 5;
  const float scale = 0.125f;
#pragma unroll
  for (int j = 0; j < 8; ++j) {
    const int n = nt * 64 + r0 + j * 8;
    const int nf = b * Nseq + n;
    const float c = cost[n * 32 + pi], s = sint[n * 32 + pi];
    const unsigned short* qp = &qkv_lin[(size_t)nf * 3072 + h * 64 + pi * 2];
    float q0 = bf2f(qp[0]), q1 = bf2f(qp[1]);
    alignas(4) unsigned short oq[2];
    oq[0] = f2bf((q0 * c - q1 * s) * scale);
    oq[1] = f2bf((q1 * c + q0 * s) * scale);
    *(unsigned int*)&qb[((size_t)bh * Nseq + n) * 64 + pi * 2] = *(const unsigned int*)oq;
    const unsigned short* kp = &qkv_lin[(size_t)nf * 3072 + 1024 + h * 64 + pi * 2];
    float k0 = bf2f(kp[0]), k1 = bf2f(kp[1]);
    alignas(4) unsigned short ok[2];
    ok[0] = f2bf(k0 * c - k1 * s);
    ok[1] = f2bf(k1 * c + k0 * s);
    *(unsigned int*)&kb[((size_t)bh * Nseq + n) * 64 + pi * 2] = *(const unsigned int*)ok;
  }
}

// ---------------- v: value-residual lerp + transpose-pack ----------------
__global__ __launch_bounds__(256)
void v_mix_pack(const unsigned short* __restrict__ qkv_lin,
                const float* __restrict__ gm,
                unsigned short* __restrict__ vres,
                unsigned short* __restrict__ vtb, int layer) {
  __shared__ unsigned short T[64][72];
  const int nt = blockIdx.x, bh = blockIdx.y;
  const int b = bh >> 4, h = bh & 15;
  const int tid = threadIdx.x;
#pragma unroll
  for (int p = 0; p < 2; ++p) {
    int c = tid + p * 256;
    int nl = c >> 3, cg = (c & 7) << 3;
    int n = nt * 64 + nl, nf = b * Nseq + n;
    uint4 vv = *(const uint4*)&qkv_lin[(size_t)nf * 3072 + 2048 + h * 64 + cg];
    if (layer == 0) {
      *(uint4*)&vres[((size_t)bh * Nseq + n) * 64 + cg] = vv;
      *(uint4*)&T[nl][cg] = vv;
    } else {
      alignas(16) unsigned short ve[8]; *(uint4*)ve = vv;
      uint4 rv = *(const uint4*)&vres[((size_t)bh * Nseq + n) * 64 + cg];
      alignas(16) unsigned short re[8]; *(uint4*)re = rv;
      const float mix = gm[(size_t)nf * 32 + 16 + h];
      alignas(16) unsigned short oe[8];
#pragma unroll
      for (int j = 0; j < 8; ++j) {
        float v = bf2f(ve[j]), rr = bf2f(re[j]);
        oe[j] = f2bf(v + mix * (rr - v));
      }
      *(uint4*)&T[nl][cg] = *(const uint4*)oe;
    }
  }
  __syncthreads();
#pragma unroll
  for (int p = 0; p < 2; ++p) {
    int c = tid + p * 256;
    int d = c >> 3, ng = (c & 7) << 3;
    alignas(16) unsigned short oe[8];
#pragma unroll
    for (int j = 0; j < 8; ++j) oe[j] = T[ng + j][d];
    *(uint4*)&vtb[(size_t)bh * 65536 + (size_t)d * Nseq + nt * 64 + ng] = *(const uint4*)oe;
  }
}

// ---------------- causal flash attention + gate + head-merge ----------------
// K/V staged via global_load_lds into XOR-swizzled LDS, shared by 4 waves;
// 2-deep ping-pong, ONE barrier per K-tile. defer-max softmax.
__global__ __launch_bounds__(256)
void attn_fwd(const unsigned short* __restrict__ qb,
              const unsigned short* __restrict__ kb,
              const unsigned short* __restrict__ vtb,
              const float* __restrict__ gm,
              unsigned short* __restrict__ attn_out) {
  __shared__ unsigned short Ks[2][64 * 64];   // [key][dh], swizzled
  __shared__ unsigned short Vs[2][64 * 64];   // V^T: [dh][key], swizzled
  __shared__ unsigned short Ps[4][16][72];
  const int bid = blockIdx.x;
  const int x = bid & 7, rest = bid >> 3;
  const int bh = x * 8 + (rest & 7);
  const int qt = 15 - (rest >> 3);
  const int b = bh >> 4, h = bh & 15;
  const int tid = threadIdx.x;
  const int w = tid >> 6, l = tid & 63;
  const int lr = l & 15, lg = l >> 4;
  const int q0 = qt * 64 + w * 16;
  const size_t head = (size_t)bh * Nseq * DH;
  const int lrow8 = l >> 3;
  const int colsw = ((l & 7) ^ lrow8) << 3;

  auto stageKV = [&](int buf, int kt) {
    const int kv0 = kt * 64;
#pragma unroll
    for (int i = 0; i < 2; ++i) {
      const int rb = w * 16 + i * 8;
      gl_lds16(&kb[head + (size_t)(kv0 + rb + lrow8) * DH + colsw],
               &Ks[buf][rb * 64]);
      gl_lds16(&vtb[head + (size_t)(rb + lrow8) * Nseq + kv0 + colsw],
               &Vs[buf][rb * 64]);
    }
  };

  bf16x8 aq[2];
  aq[0] = *(const bf16x8*)&qb[head + (size_t)(q0 + lr) * DH + lg * 8];
  aq[1] = *(const bf16x8*)&qb[head + (size_t)(q0 + lr) * DH + 32 + lg * 8];

  float mrow[4] = {-1e30f, -1e30f, -1e30f, -1e30f};
  float lsum[4] = {0.f, 0.f, 0.f, 0.f};
  f32x4 acco[4] = {};

  stageKV(0, 0);
  asm volatile("s_waitcnt vmcnt(0)" ::: "memory");
  __builtin_amdgcn_s_barrier();
  fence_mem();

#pragma unroll 1
  for (int kt = 0; kt <= qt; ++kt) {
    const int p = kt & 1;
    const int kv0 = kt * 64;
    const bool more = (kt < qt);
    if (more) stageKV(p ^ 1, kt + 1);      // async prefetch next K/V tile
    f32x4 s[4];
#pragma unroll
    for (int t = 0; t < 4; ++t) {
      const int krow = t * 16 + lr;
      bf16x8 bk0 = *(const bf16x8*)&Ks[p][krow * 64 + ((0 + lg) ^ (lr & 7)) * 8];
      bf16x8 bk1 = *(const bf16x8*)&Ks[p][krow * 64 + ((4 + lg) ^ (lr & 7)) * 8];
      f32x4 z = {};
      z = __builtin_amdgcn_mfma_f32_16x16x32_bf16(aq[0], bk0, z, 0, 0, 0);
      z = __builtin_amdgcn_mfma_f32_16x16x32_bf16(aq[1], bk1, z, 0, 0, 0);
      s[t] = z;
    }
    const bool diag = (kt == qt);
    float mx4[4];
    bool need = false;
#pragma unroll
    for (int r = 0; r < 4; ++r) {
      const int qr = q0 + lg * 4 + r;
      float mx = -1e30f;
#pragma unroll
      for (int t = 0; t < 4; ++t) {
        float sv = s[t][r];
        if (diag && (kv0 + t * 16 + lr > qr)) sv = -1e30f;
        s[t][r] = sv;
        mx = fmaxf(mx, sv);
      }
      mx = fmaxf(mx, __shfl_xor(mx, 1, 64));
      mx = fmaxf(mx, __shfl_xor(mx, 2, 64));
      mx = fmaxf(mx, __shfl_xor(mx, 4, 64));
      mx = fmaxf(mx, __shfl_xor(mx, 8, 64));
      mx4[r] = mx;
      need = need || (mx > mrow[r] + 8.0f);
    }
    if (__any(need)) {    // defer-max
#pragma unroll
      for (int r = 0; r < 4; ++r) {
        const float mn = fmaxf(mrow[r], mx4[r]);
        const float alpha = __expf(mrow[r] - mn);
        mrow[r] = mn;
        lsum[r] *= alpha;
#pragma unroll
        for (int dt = 0; dt < 4; ++dt) acco[dt][r] *= alpha;
      }
    }
#pragma unroll
    for (int r = 0; r < 4; ++r) {
      float rs = 0.f;
#pragma unroll
      for (int t = 0; t < 4; ++t) {
        float pv = __expf(s[t][r] - mrow[r]);   // bounded by e^8
        s[t][r] = pv;
        rs += pv;
      }
      rs += __shfl_xor(rs, 1, 64);
      rs += __shfl_xor(rs, 2, 64);
      rs += __shfl_xor(rs, 4, 64);
      rs += __shfl_xor(rs, 8, 64);
      lsum[r] += rs;
    }
#pragma unroll
    for (int t = 0; t < 4; ++t)
#pragma unroll
      for (int r = 0; r < 4; ++r)
        Ps[w][lg * 4 + r][t * 16 + lr] = f2bf(s[t][r]);
#pragma unroll
    for (int ks = 0; ks < 2; ++ks) {
      bf16x8 ap = *(const bf16x8*)&Ps[w][lr][ks * 32 + lg * 8];
#pragma unroll
      for (int dt = 0; dt < 4; ++dt) {
        const int vrow = dt * 16 + lr;
        bf16x8 bv = *(const bf16x8*)&Vs[p][vrow * 64 + ((ks * 4 + lg) ^ (lr & 7)) * 8];
        acco[dt] = __builtin_amdgcn_mfma_f32_16x16x32_bf16(ap, bv, acco[dt], 0, 0, 0);
      }
    }
    if (more) {
      asm volatile("s_waitcnt vmcnt(0)" ::: "memory");  // next tile landed
      __builtin_amdgcn_s_barrier();                     // all waves done with buf p
      fence_mem();
    }
  }

#pragma unroll
  for (int r = 0; r < 4; ++r) {
    const int qr = q0 + lg * 4 + r;
    const int nf = b * Nseq + qr;
    const float gate = gm[(size_t)nf * 32 + h];
    const float inv = 1.0f / lsum[r];
#pragma unroll
    for (int dt = 0; dt < 4; ++dt)
      attn_out[(size_t)nf * Dm + h * DH + dt * 16 + lr] = f2bf(acco[dt][r] * inv * gate);
  }
}

// ---------------- host launch ----------------
extern "C" void kernel_launch(void* const* d_in, const int* in_sizes, int n_in,
                              void* d_out, int out_size, void* d_ws, size_t ws_size,
                              hipStream_t stream) {
  const float* x_in  = (const float*)d_in[0];
  const float* naw   = (const float*)d_in[1];
  const float* wq    = (const float*)d_in[2];
  const float* wkv   = (const float*)d_in[3];
  const float* wo    = (const float*)d_in[4];
  const float* wg    = (const float*)d_in[5];
  const float* wmix  = (const float*)d_in[6];
  const float* nfw   = (const float*)d_in[7];
  const float* ffw   = (const float*)d_in[8];
  const float* w_in  = (const float*)d_in[9];
  const float* b_in  = (const float*)d_in[10];
  const float* w_out = (const float*)d_in[11];
  const float* b_out = (const float*)d_in[12];
  const float* fnw   = (const float*)d_in[13];

  uint8_t* ws = (uint8_t*)d_ws;
  size_t off = 0;
  auto alloc = [&](size_t bytes) -> void* {
    void* p = ws + off;
    off += (bytes + 255) & ~(size_t)255;
    return p;
  };
  float*          x_res    = (float*)alloc((size_t)ROWS * Dm * 4);
  unsigned short* h        = (unsigned short*)alloc((size_t)ROWS * Dm * 2);
  unsigned short* qkv_lin  = (unsigned short*)alloc((size_t)ROWS * 3072 * 2);
  float*          gm       = (float*)alloc((size_t)ROWS * 32 * 4);
  unsigned short* qb       = (unsigned short*)alloc((size_t)64 * Nseq * DH * 2);
  unsigned short* kb       = (unsigned short*)alloc((size_t)64 * Nseq * DH * 2);
  unsigned short* vtb      = (unsigned short*)alloc((size_t)64 * Nseq * DH * 2);
  unsigned short* vres     = (unsigned short*)alloc((size_t)64 * Nseq * DH * 2);
  unsigned short* attn     = (unsigned short*)alloc((size_t)ROWS * Dm * 2);
  float*          cost     = (float*)alloc((size_t)Nseq * 32 * 4);
  float*          sint     = (float*)alloc((size_t)Nseq * 32 * 4);
  unsigned short* wqkv_bf  = (unsigned short*)alloc((size_t)NQKV * 1024 * 2);
  unsigned short* wo_bf    = (unsigned short*)alloc((size_t)1024 * 1024 * 2);
  unsigned short* win_bf   = (unsigned short*)alloc((size_t)WIDE * 1024 * 2);  // 16-row groups
  unsigned short* wout_bf  = (unsigned short*)alloc((size_t)1024 * FI_PAD * 2);
  unsigned short* u = qkv_lin;  // alias: qkv scratch dead before FF uses u

  hipMemcpyAsync(x_res, x_in, (size_t)ROWS * Dm * 4, hipMemcpyDeviceToDevice, stream);
  rope_tables<<<128, 256, 0, stream>>>(cost, sint);

  for (int i = 0; i < NDEPTH; ++i) {
    convf2b<<<dim3(1, 1024), 128, 0, stream>>>(wq + (size_t)i * 1024 * 1024, wqkv_bf, 1024, 1024, 1024);
    convf2b<<<dim3(1, 2048), 128, 0, stream>>>(wkv + (size_t)i * 2048 * 1024, wqkv_bf + (size_t)1024 * 1024, 2048, 1024, 1024);
    convf2b<<<dim3(1, 16), 128, 0, stream>>>(wg + (size_t)i * 16 * 1024, wqkv_bf + (size_t)3072 * 1024, 16, 1024, 1024);
    convf2b<<<dim3(1, 16), 128, 0, stream>>>(wmix + (size_t)i * 16 * 1024, wqkv_bf + (size_t)3088 * 1024, 16, 1024, 1024);
    convf2b<<<dim3(1, 224), 128, 0, stream>>>(wg, wqkv_bf + (size_t)3104 * 1024, 0, 1024, 1024);  // zero pad rows
    convf2b<<<dim3(1, 1024), 128, 0, stream>>>(wo + (size_t)i * 1024 * 1024, wo_bf, 1024, 1024, 1024);
    convf2b_g16<<<dim3(1, WIDE), 128, 0, stream>>>(w_in + (size_t)i * 2 * FI * 1024, win_bf);
    convf2b<<<dim3(2, 1024), 256, 0, stream>>>(w_out + (size_t)i * 1024 * FI, wout_bf, 1024, FI, FI_PAD);

    rms_one<<<ROWS, 256, 0, stream>>>(x_res, naw + i * 1024, h);
    gemm_nt256<4><<<208, 512, 0, stream>>>(h, wqkv_bf, qkv_lin, gm, 1024, 3072, 16, 13);
    rope_qk<<<dim3(16, 64), 256, 0, stream>>>(qkv_lin, cost, sint, qb, kb);
    v_mix_pack<<<dim3(16, 64), 256, 0, stream>>>(qkv_lin, gm, vres, vtb, i);
    attn_fwd<<<1024, 256, 0, stream>>>(qb, kb, vtb, gm, attn);
    gemm_nt<2><<<dim3(32, 8), 256, 0, stream>>>(attn, wo_bf, x_res, nullptr, x_res, 1024, 1024, 1024);
    rms_ff<<<ROWS, 256, 0, stream>>>(x_res, nfw + i * 1024, ffw + i * 1024, h);
    gemm_nt256<3><<<352, 512, 0, stream>>>(h, win_bf, u, b_in + (size_t)i * 2 * FI, 1024, FI_PAD, 16, 22);
    gemm_nt<2><<<dim3(32, 8), 256, 0, stream>>>(u, wout_bf, x_res, b_out + i * 1024, x_res, FI_PAD, 1024, 1024);
  }
  rms_final<<<ROWS, 256, 0, stream>>>(x_res, fnw, (float*)d_out);
}

// Round 16
// 1330.498 us; speedup vs baseline: 1.0528x; 1.0528x over previous
//
#include <hip/hip_runtime.h>
#include <cstdint>
#include <cstddef>

// TransformerXL forward (B=4,N=1024,D=1024,H=16,DH=64,DEPTH=4, GEGLU FI=2730)
// R16: rollback of R15's qkv+gm fusion (the regressor). Base = R14 structure
//      (separate sigmoid GEMM, 192-block qkv) keeping only R15's proven-neutral
//      intra-tile barrier drop in gemm_nt256.

#define DEV_INLINE __device__ __forceinline__

typedef short bf16x8 __attribute__((ext_vector_type(8)));
typedef float f32x4 __attribute__((ext_vector_type(4)));

constexpr int Bsz = 4, Nseq = 1024, Dm = 1024, Hh = 16, DH = 64, NDEPTH = 4;
constexpr int FI = 2730;        // GEGLU inner dim
constexpr int FI_PAD = 2752;    // u cols padded to /64 (zero-filled)
constexpr int FI_TILE = 2816;   // per-half weight rows padded to /128
constexpr int WIDE = 2 * FI_TILE;  // 5632: 16-row groups [16a | 16g | ...]
constexpr int ROWS = Bsz * Nseq; // 4096
constexpr float EPSR = 1.1920929e-07f;

DEV_INLINE float bf2f(unsigned short u) {
  unsigned int x = ((unsigned int)u) << 16;
  float f; __builtin_memcpy(&f, &x, 4); return f;
}
DEV_INLINE unsigned short f2bf(float f) {
  unsigned int x; __builtin_memcpy(&x, &f, 4);
  unsigned int r = x + 0x7fffu + ((x >> 16) & 1u);  // RNE
  return (unsigned short)(r >> 16);
}

using gptr_t = const __attribute__((address_space(1))) void*;
using lptr_t = __attribute__((address_space(3))) void*;
DEV_INLINE void gl_lds16(const void* g, void* l) {
  __builtin_amdgcn_global_load_lds((gptr_t)g, (lptr_t)l, 16, 0, 0);
}
DEV_INLINE void fence_mem() { asm volatile("" ::: "memory"); }

// ---------------- weight fp32 -> bf16 (vectorized, with zero padding) -----------
__global__ __launch_bounds__(256)
void convf2b(const float* __restrict__ src, unsigned short* __restrict__ dst,
             int src_rows, int src_cols, int dst_cols) {
  const int r = blockIdx.y;
  const int c8 = (blockIdx.x * blockDim.x + threadIdx.x) * 8;
  if (c8 >= dst_cols) return;
  alignas(16) unsigned short o[8];
  if (r < src_rows && c8 + 8 <= src_cols) {
    const float2* p = (const float2*)&src[(size_t)r * src_cols + c8];
    const float2 v0 = p[0], v1 = p[1], v2 = p[2], v3 = p[3];
    o[0] = f2bf(v0.x); o[1] = f2bf(v0.y); o[2] = f2bf(v1.x); o[3] = f2bf(v1.y);
    o[4] = f2bf(v2.x); o[5] = f2bf(v2.y); o[6] = f2bf(v3.x); o[7] = f2bf(v3.y);
  } else {
#pragma unroll
    for (int j = 0; j < 8; ++j) {
      const int c = c8 + j;
      float v = (r < src_rows && c < src_cols) ? src[(size_t)r * src_cols + c] : 0.0f;
      o[j] = f2bf(v);
    }
  }
  *(uint4*)&dst[(size_t)r * dst_cols + c8] = *(const uint4*)o;
}

// w_in 16-row-group interleave: dst rows [32t..32t+16) = a[16t..), [+16..32) = g
__global__ __launch_bounds__(128)
void convf2b_g16(const float* __restrict__ src, unsigned short* __restrict__ dst) {
  const int p = blockIdx.y;           // 0..WIDE-1
  const int c8 = threadIdx.x * 8;     // 128 thr * 8 = 1024 cols
  const int t = p >> 5, r5 = p & 31;
  const int srow = t * 16 + (r5 & 15);
  alignas(16) unsigned short o[8];
  if (srow < FI) {
    const size_t base = ((size_t)((r5 < 16) ? 0 : 1) * FI + srow) * 1024 + c8;
    const float4 v0 = *(const float4*)&src[base];
    const float4 v1 = *(const float4*)&src[base + 4];
    o[0]=f2bf(v0.x); o[1]=f2bf(v0.y); o[2]=f2bf(v0.z); o[3]=f2bf(v0.w);
    o[4]=f2bf(v1.x); o[5]=f2bf(v1.y); o[6]=f2bf(v1.z); o[7]=f2bf(v1.w);
  } else {
#pragma unroll
    for (int j = 0; j < 8; ++j) o[j] = 0;
  }
  *(uint4*)&dst[(size_t)p * 1024 + c8] = *(const uint4*)o;
}

// ---------------- rope cos/sin tables ----------------
__global__ __launch_bounds__(256)
void rope_tables(float* __restrict__ cost, float* __restrict__ sint) {
  int idx = blockIdx.x * 256 + threadIdx.x;
  if (idx >= Nseq * 32) return;
  int n = idx >> 5, p = idx & 31;
  float freq = powf(10000.0f, -(float)(2 * p) * (1.0f / 64.0f));
  float ang = (float)n * freq;
  cost[idx] = cosf(ang);
  sint[idx] = sinf(ang);
}

// ---------------- RMSNorm variants ----------------
__global__ __launch_bounds__(256)
void rms_one(const float* __restrict__ x, const float* __restrict__ w,
             unsigned short* __restrict__ out) {
  __shared__ float sred[4];
  const int row = blockIdx.x, tid = threadIdx.x;
  const float4 v = ((const float4*)(x + (size_t)row * Dm))[tid];
  float ss = v.x * v.x + v.y * v.y + v.z * v.z + v.w * v.w;
#pragma unroll
  for (int o = 32; o >= 1; o >>= 1) ss += __shfl_xor(ss, o, 64);
  if ((tid & 63) == 0) sred[tid >> 6] = ss;
  __syncthreads();
  float rs = rsqrtf((sred[0] + sred[1] + sred[2] + sred[3]) * (1.0f / Dm) + EPSR);
  const float4 wv = ((const float4*)w)[tid];
  alignas(8) unsigned short o4[4] = { f2bf(v.x * rs * wv.x), f2bf(v.y * rs * wv.y),
                                      f2bf(v.z * rs * wv.z), f2bf(v.w * rs * wv.w) };
  *(uint2*)&out[(size_t)row * Dm + tid * 4] = *(const uint2*)o4;
}

__global__ __launch_bounds__(256)
void rms_ff(const float* __restrict__ x, const float* __restrict__ w1,
            const float* __restrict__ w2, unsigned short* __restrict__ out) {
  __shared__ float sred[4];
  const int row = blockIdx.x, tid = threadIdx.x;
  const float4 v = ((const float4*)(x + (size_t)row * Dm))[tid];
  const float4 w1v = ((const float4*)w1)[tid];
  const float4 w2v = ((const float4*)w2)[tid];
  float ss = v.x * v.x + v.y * v.y + v.z * v.z + v.w * v.w;
#pragma unroll
  for (int o = 32; o >= 1; o >>= 1) ss += __shfl_xor(ss, o, 64);
  if ((tid & 63) == 0) sred[tid >> 6] = ss;
  __syncthreads();
  float rs1 = rsqrtf((sred[0] + sred[1] + sred[2] + sred[3]) * (1.0f / Dm) + EPSR);
  float t0 = v.x * rs1 * w1v.x, t1 = v.y * rs1 * w1v.y;
  float t2 = v.z * rs1 * w1v.z, t3 = v.w * rs1 * w1v.w;
  float ss2 = t0 * t0 + t1 * t1 + t2 * t2 + t3 * t3;
#pragma unroll
  for (int o = 32; o >= 1; o >>= 1) ss2 += __shfl_xor(ss2, o, 64);
  __syncthreads();
  if ((tid & 63) == 0) sred[tid >> 6] = ss2;
  __syncthreads();
  float rs2 = rsqrtf((sred[0] + sred[1] + sred[2] + sred[3]) * (1.0f / Dm) + EPSR);
  alignas(8) unsigned short o4[4] = { f2bf(t0 * rs2 * w2v.x), f2bf(t1 * rs2 * w2v.y),
                                      f2bf(t2 * rs2 * w2v.z), f2bf(t3 * rs2 * w2v.w) };
  *(uint2*)&out[(size_t)row * Dm + tid * 4] = *(const uint2*)o4;
}

__global__ __launch_bounds__(256)
void rms_final(const float* __restrict__ x, const float* __restrict__ w,
               float* __restrict__ out) {
  __shared__ float sred[4];
  const int row = blockIdx.x, tid = threadIdx.x;
  const float4 v = ((const float4*)(x + (size_t)row * Dm))[tid];
  float ss = v.x * v.x + v.y * v.y + v.z * v.z + v.w * v.w;
#pragma unroll
  for (int o = 32; o >= 1; o >>= 1) ss += __shfl_xor(ss, o, 64);
  if ((tid & 63) == 0) sred[tid >> 6] = ss;
  __syncthreads();
  float rs = rsqrtf((sred[0] + sred[1] + sred[2] + sred[3]) * (1.0f / Dm) + EPSR);
  const float4 wv = ((const float4*)w)[tid];
  float4 o;
  o.x = v.x * rs * wv.x; o.y = v.y * rs * wv.y;
  o.z = v.z * rs * wv.z; o.w = v.w * rs * wv.w;
  ((float4*)(out + (size_t)row * Dm))[tid] = o;
}

// ---------------- 128x128 NT GEMM (R9 schedule) ----------------
// MODE: 1=sigmoid f32, 2=f32 residual(+bias)
template <int MODE>
__global__ __launch_bounds__(256)
void gemm_nt(const unsigned short* __restrict__ A,
             const unsigned short* __restrict__ Bw,
             void* __restrict__ Cout,
             const float* __restrict__ bias,
             const float* __restrict__ resid,
             int K, int ldc, int n_store) {
  __shared__ unsigned short As[2][128 * 64];
  __shared__ unsigned short Bs[2][128 * 64];
  const int tid = threadIdx.x;
  const int m0 = blockIdx.x * 128;
  const int n0 = blockIdx.y * 128;
  const int w = tid >> 6, l = tid & 63;
  const int wm = (w >> 1) * 64, wn = (w & 1) * 64;
  const int lr = l & 15, lg = l >> 4;
  const int lsub = l & 7, lrow8 = l >> 3;
  const int colsw = (lsub ^ lrow8) << 3;
  const unsigned short* gA = &A[(size_t)(m0 + w * 8 + lrow8) * K + colsw];
  const unsigned short* gB = &Bw[(size_t)(n0 + w * 8 + lrow8) * K + colsw];
  const size_t rstep = (size_t)32 * K;
  f32x4 acc[4][4] = {};

  auto stage = [&](int buf, int kt) {
    const int o = kt * 64;
#pragma unroll
    for (int i = 0; i < 4; ++i) {
      gl_lds16(gA + i * rstep + o, &As[buf][i * 2048 + w * 512]);
      gl_lds16(gB + i * rstep + o, &Bs[buf][i * 2048 + w * 512]);
    }
  };
  auto compute = [&](int buf) {
    bf16x8 af[2][4], bfr[2][4];
#pragma unroll
    for (int ks = 0; ks < 2; ++ks) {
      const int slot = (ks * 4 + lg) ^ (lr & 7);
#pragma unroll
      for (int fj = 0; fj < 4; ++fj)
        bfr[ks][fj] = *(const bf16x8*)&Bs[buf][(wn + fj * 16 + lr) * 64 + slot * 8];
#pragma unroll
      for (int fi = 0; fi < 4; ++fi)
        af[ks][fi] = *(const bf16x8*)&As[buf][(wm + fi * 16 + lr) * 64 + slot * 8];
    }
    __builtin_amdgcn_s_setprio(1);
#pragma unroll
    for (int ks = 0; ks < 2; ++ks)
#pragma unroll
      for (int fi = 0; fi < 4; ++fi)
#pragma unroll
        for (int fj = 0; fj < 4; ++fj)
          acc[fi][fj] = __builtin_amdgcn_mfma_f32_16x16x32_bf16(af[ks][fi], bfr[ks][fj], acc[fi][fj], 0, 0, 0);
    __builtin_amdgcn_s_setprio(0);
  };

  const int nk = K >> 6;
  stage(0, 0);
  asm volatile("s_waitcnt vmcnt(0)" ::: "memory");
  __builtin_amdgcn_s_barrier();
  fence_mem();
  int cur = 0;
#pragma unroll 1
  for (int kt = 0; kt < nk; ++kt) {
    const bool more = (kt + 1 < nk);
    if (more) stage(cur ^ 1, kt + 1);
    compute(cur);
    if (more) {
      asm volatile("s_waitcnt vmcnt(0)" ::: "memory");
      __builtin_amdgcn_s_barrier();
      fence_mem();
    }
    cur ^= 1;
  }

#pragma unroll
  for (int fi = 0; fi < 4; ++fi) {
    const int rowb = m0 + wm + fi * 16 + lg * 4;
#pragma unroll
    for (int fj = 0; fj < 4; ++fj) {
      const int col = n0 + wn + fj * 16 + lr;
#pragma unroll
      for (int r = 0; r < 4; ++r) {
        const float val = acc[fi][fj][r];
        const int rr = rowb + r;
        if constexpr (MODE == 1) {
          if (col < n_store)
            ((float*)Cout)[(size_t)rr * ldc + col] = 1.0f / (1.0f + __expf(-val));
        } else {  // MODE 2
          const float bv = bias ? bias[col] : 0.0f;
          ((float*)Cout)[(size_t)rr * ldc + col] =
              resid[(size_t)rr * ldc + col] + val + bv;
        }
      }
    }
  }
}

// ---------------- 256x256 NT GEMM: 512 thr, 8 waves (2Mx4N), BK=64 ----------------
// 4 stage-parts per K-tile; NO intra-tile barriers (reads hit buf p, stages
// hit p^1); tile-end vmcnt(0)+barrier only. XCD swizzle.
// MODE: 0=bf16 store, 3=grouped GEGLU (a/g pairs in same thread)
template <int MODE>
__global__ __launch_bounds__(512, 2)
void gemm_nt256(const unsigned short* __restrict__ A,
                const unsigned short* __restrict__ Bw,
                void* __restrict__ Cout,
                const float* __restrict__ bias,
                int K, int ldc, int nm, int nn) {
  __shared__ unsigned short As[2][256 * 64];
  __shared__ unsigned short Bs[2][256 * 64];
  const int tid = threadIdx.x;
  const int nwg = nm * nn;
  const int qq = nwg >> 3;
  const int xcd = blockIdx.x & 7, orig = blockIdx.x >> 3;
  const int wgid = xcd * qq + orig;
  const int m0 = (wgid % nm) * 256;
  const int n0 = (wgid / nm) * 256;
  const int w = tid >> 6, l = tid & 63;
  const int wm = (w >> 2) * 128, wn = (w & 3) * 64;
  const int lr = l & 15, lg = l >> 4;
  const int lsub = l & 7, lrow8 = l >> 3;
  const int colsw = (lsub ^ lrow8) << 3;
  const unsigned short* gA = &A[(size_t)(m0 + w * 8 + lrow8) * K + colsw];
  const unsigned short* gB = &Bw[(size_t)(n0 + w * 8 + lrow8) * K + colsw];
  const size_t rstep = (size_t)64 * K;
  f32x4 acc[8][4] = {};

  // part: 0 = A rows 0-127, 1 = A rows 128-255, 2 = B rows 0-127, 3 = B hi
  auto stage_part = [&](int buf, int kt, int part) {
    const int o = kt * 64;
    const int i0 = (part & 1) * 2;
    if (part < 2) {
      gl_lds16(gA + (size_t)i0 * rstep + o,       &As[buf][i0 * 4096 + w * 512]);
      gl_lds16(gA + (size_t)(i0 + 1) * rstep + o, &As[buf][(i0 + 1) * 4096 + w * 512]);
    } else {
      gl_lds16(gB + (size_t)i0 * rstep + o,       &Bs[buf][i0 * 4096 + w * 512]);
      gl_lds16(gB + (size_t)(i0 + 1) * rstep + o, &Bs[buf][(i0 + 1) * 4096 + w * 512]);
    }
  };

  const int nk = K >> 6;
  stage_part(0, 0, 0); stage_part(0, 0, 1);
  stage_part(0, 0, 2); stage_part(0, 0, 3);
  asm volatile("s_waitcnt vmcnt(0)" ::: "memory");
  __builtin_amdgcn_s_barrier();
  fence_mem();

#pragma unroll 1
  for (int t = 0; t < nk; ++t) {
    const int p = t & 1;
    const bool more = (t + 1 < nk);
    bf16x8 bfr[4];
#pragma unroll
    for (int q = 0; q < 4; ++q) {
      const int ks = q >> 1, half = q & 1;
      const int slot = (ks * 4 + lg) ^ (lr & 7);
      if (half == 0) {
#pragma unroll
        for (int fj = 0; fj < 4; ++fj)
          bfr[fj] = *(const bf16x8*)&Bs[p][(wn + fj * 16 + lr) * 64 + slot * 8];
      }
      bf16x8 af[4];
#pragma unroll
      for (int fi = 0; fi < 4; ++fi)
        af[fi] = *(const bf16x8*)&As[p][(wm + half * 64 + fi * 16 + lr) * 64 + slot * 8];
      if (more) stage_part(p ^ 1, t + 1, q);   // one half-tile per phase
      __builtin_amdgcn_s_setprio(1);
#pragma unroll
      for (int fi = 0; fi < 4; ++fi)
#pragma unroll
        for (int fj = 0; fj < 4; ++fj)
          acc[half * 4 + fi][fj] =
              __builtin_amdgcn_mfma_f32_16x16x32_bf16(af[fi], bfr[fj], acc[half * 4 + fi][fj], 0, 0, 0);
      __builtin_amdgcn_s_setprio(0);
      // no intra-tile barrier (reads from buf p only; stages to p^1 only)
    }
    if (more) {
      asm volatile("s_waitcnt vmcnt(0)" ::: "memory");  // tile t+1 landed
      __builtin_amdgcn_s_barrier();                     // block-wide; buf p free
      fence_mem();
    }
  }

#pragma unroll
  for (int fi = 0; fi < 8; ++fi) {
    const int rowb = m0 + wm + fi * 16 + lg * 4;
    if constexpr (MODE == 0) {
#pragma unroll
      for (int fj = 0; fj < 4; ++fj) {
        const int col = n0 + wn + fj * 16 + lr;
#pragma unroll
        for (int r = 0; r < 4; ++r)
          ((unsigned short*)Cout)[(size_t)(rowb + r) * ldc + col] = f2bf(acc[fi][fj][r]);
      }
    } else {  // MODE 3: cols in 16-groups [a|g]; pair (2*fjp, 2*fjp+1) in-thread
#pragma unroll
      for (int fjp = 0; fjp < 2; ++fjp) {
        const int ucol = ((n0 + wn) >> 1) + fjp * 16 + lr;
        if (ucol >= FI_PAD) continue;
        const bool live = (ucol < FI);
        const float ba = live ? bias[ucol] : 0.0f;
        const float bg = live ? bias[FI + ucol] : 0.0f;
#pragma unroll
        for (int r = 0; r < 4; ++r) {
          const float va = acc[fi][2 * fjp][r] + ba;
          const float vg = acc[fi][2 * fjp + 1][r] + bg;
          const float gel = 0.5f * vg * (1.0f + erff(vg * 0.70710678118654752f));
          ((unsigned short*)Cout)[(size_t)(rowb + r) * ldc + ucol] =
              f2bf(live ? va * gel : 0.0f);
        }
      }
    }
  }
}

// ---------------- RoPE on q,k (q also * DH^-0.5) ----------------
__global__ __launch_bounds__(256)
void rope_qk(const unsigned short* __restrict__ qkv_lin,
             const float* __restrict__ cost, const float* __restrict__ sint,
             unsigned short* __restrict__ qb, unsigned short* __restrict__ kb) {
  const int nt = blockIdx.x, bh = blockIdx.y;
  const int b = bh >> 4, h = bh & 15;
  const int tid = threadIdx.x;
  const int pi = tid & 31, r0 = tid >> 5;
  const float scale = 0.125f;
#pragma unroll
  for (int j = 0; j < 8; ++j) {
    const int n = nt * 64 + r0 + j * 8;
    const int nf = b * Nseq + n;
    const float c = cost[n * 32 + pi], s = sint[n * 32 + pi];
    const unsigned short* qp = &qkv_lin[(size_t)nf * 3072 + h * 64 + pi * 2];
    float q0 = bf2f(qp[0]), q1 = bf2f(qp[1]);
    alignas(4) unsigned short oq[2];
    oq[0] = f2bf((q0 * c - q1 * s) * scale);
    oq[1] = f2bf((q1 * c + q0 * s) * scale);
    *(unsigned int*)&qb[((size_t)bh * Nseq + n) * 64 + pi * 2] = *(const unsigned int*)oq;
    const unsigned short* kp = &qkv_lin[(size_t)nf * 3072 + 1024 + h * 64 + pi * 2];
    float k0 = bf2f(kp[0]), k1 = bf2f(kp[1]);
    alignas(4) unsigned short ok[2];
    ok[0] = f2bf(k0 * c - k1 * s);
    ok[1] = f2bf(k1 * c + k0 * s);
    *(unsigned int*)&kb[((size_t)bh * Nseq + n) * 64 + pi * 2] = *(const unsigned int*)ok;
  }
}

// ---------------- v: value-residual lerp + transpose-pack ----------------
__global__ __launch_bounds__(256)
void v_mix_pack(const unsigned short* __restrict__ qkv_lin,
                const float* __restrict__ gm,
                unsigned short* __restrict__ vres,
                unsigned short* __restrict__ vtb, int layer) {
  __shared__ unsigned short T[64][72];
  const int nt = blockIdx.x, bh = blockIdx.y;
  const int b = bh >> 4, h = bh & 15;
  const int tid = threadIdx.x;
#pragma unroll
  for (int p = 0; p < 2; ++p) {
    int c = tid + p * 256;
    int nl = c >> 3, cg = (c & 7) << 3;
    int n = nt * 64 + nl, nf = b * Nseq + n;
    uint4 vv = *(const uint4*)&qkv_lin[(size_t)nf * 3072 + 2048 + h * 64 + cg];
    if (layer == 0) {
      *(uint4*)&vres[((size_t)bh * Nseq + n) * 64 + cg] = vv;
      *(uint4*)&T[nl][cg] = vv;
    } else {
      alignas(16) unsigned short ve[8]; *(uint4*)ve = vv;
      uint4 rv = *(const uint4*)&vres[((size_t)bh * Nseq + n) * 64 + cg];
      alignas(16) unsigned short re[8]; *(uint4*)re = rv;
      const float mix = gm[(size_t)nf * 32 + 16 + h];
      alignas(16) unsigned short oe[8];
#pragma unroll
      for (int j = 0; j < 8; ++j) {
        float v = bf2f(ve[j]), rr = bf2f(re[j]);
        oe[j] = f2bf(v + mix * (rr - v));
      }
      *(uint4*)&T[nl][cg] = *(const uint4*)oe;
    }
  }
  __syncthreads();
#pragma unroll
  for (int p = 0; p < 2; ++p) {
    int c = tid + p * 256;
    int d = c >> 3, ng = (c & 7) << 3;
    alignas(16) unsigned short oe[8];
#pragma unroll
    for (int j = 0; j < 8; ++j) oe[j] = T[ng + j][d];
    *(uint4*)&vtb[(size_t)bh * 65536 + (size_t)d * Nseq + nt * 64 + ng] = *(const uint4*)oe;
  }
}

// ---------------- causal flash attention + gate + head-merge ----------------
// K/V staged via global_load_lds into XOR-swizzled LDS, shared by 4 waves;
// 2-deep ping-pong, ONE barrier per K-tile. defer-max softmax.
__global__ __launch_bounds__(256)
void attn_fwd(const unsigned short* __restrict__ qb,
              const unsigned short* __restrict__ kb,
              const unsigned short* __restrict__ vtb,
              const float* __restrict__ gm,
              unsigned short* __restrict__ attn_out) {
  __shared__ unsigned short Ks[2][64 * 64];   // [key][dh], swizzled
  __shared__ unsigned short Vs[2][64 * 64];   // V^T: [dh][key], swizzled
  __shared__ unsigned short Ps[4][16][72];
  const int bid = blockIdx.x;
  const int x = bid & 7, rest = bid >> 3;
  const int bh = x * 8 + (rest & 7);
  const int qt = 15 - (rest >> 3);
  const int b = bh >> 4, h = bh & 15;
  const int tid = threadIdx.x;
  const int w = tid >> 6, l = tid & 63;
  const int lr = l & 15, lg = l >> 4;
  const int q0 = qt * 64 + w * 16;
  const size_t head = (size_t)bh * Nseq * DH;
  const int lrow8 = l >> 3;
  const int colsw = ((l & 7) ^ lrow8) << 3;

  auto stageKV = [&](int buf, int kt) {
    const int kv0 = kt * 64;
#pragma unroll
    for (int i = 0; i < 2; ++i) {
      const int rb = w * 16 + i * 8;
      gl_lds16(&kb[head + (size_t)(kv0 + rb + lrow8) * DH + colsw],
               &Ks[buf][rb * 64]);
      gl_lds16(&vtb[head + (size_t)(rb + lrow8) * Nseq + kv0 + colsw],
               &Vs[buf][rb * 64]);
    }
  };

  bf16x8 aq[2];
  aq[0] = *(const bf16x8*)&qb[head + (size_t)(q0 + lr) * DH + lg * 8];
  aq[1] = *(const bf16x8*)&qb[head + (size_t)(q0 + lr) * DH + 32 + lg * 8];

  float mrow[4] = {-1e30f, -1e30f, -1e30f, -1e30f};
  float lsum[4] = {0.f, 0.f, 0.f, 0.f};
  f32x4 acco[4] = {};

  stageKV(0, 0);
  asm volatile("s_waitcnt vmcnt(0)" ::: "memory");
  __builtin_amdgcn_s_barrier();
  fence_mem();

#pragma unroll 1
  for (int kt = 0; kt <= qt; ++kt) {
    const int p = kt & 1;
    const int kv0 = kt * 64;
    const bool more = (kt < qt);
    if (more) stageKV(p ^ 1, kt + 1);      // async prefetch next K/V tile
    f32x4 s[4];
#pragma unroll
    for (int t = 0; t < 4; ++t) {
      const int krow = t * 16 + lr;
      bf16x8 bk0 = *(const bf16x8*)&Ks[p][krow * 64 + ((0 + lg) ^ (lr & 7)) * 8];
      bf16x8 bk1 = *(const bf16x8*)&Ks[p][krow * 64 + ((4 + lg) ^ (lr & 7)) * 8];
      f32x4 z = {};
      z = __builtin_amdgcn_mfma_f32_16x16x32_bf16(aq[0], bk0, z, 0, 0, 0);
      z = __builtin_amdgcn_mfma_f32_16x16x32_bf16(aq[1], bk1, z, 0, 0, 0);
      s[t] = z;
    }
    const bool diag = (kt == qt);
    float mx4[4];
    bool need = false;
#pragma unroll
    for (int r = 0; r < 4; ++r) {
      const int qr = q0 + lg * 4 + r;
      float mx = -1e30f;
#pragma unroll
      for (int t = 0; t < 4; ++t) {
        float sv = s[t][r];
        if (diag && (kv0 + t * 16 + lr > qr)) sv = -1e30f;
        s[t][r] = sv;
        mx = fmaxf(mx, sv);
      }
      mx = fmaxf(mx, __shfl_xor(mx, 1, 64));
      mx = fmaxf(mx, __shfl_xor(mx, 2, 64));
      mx = fmaxf(mx, __shfl_xor(mx, 4, 64));
      mx = fmaxf(mx, __shfl_xor(mx, 8, 64));
      mx4[r] = mx;
      need = need || (mx > mrow[r] + 8.0f);
    }
    if (__any(need)) {    // defer-max
#pragma unroll
      for (int r = 0; r < 4; ++r) {
        const float mn = fmaxf(mrow[r], mx4[r]);
        const float alpha = __expf(mrow[r] - mn);
        mrow[r] = mn;
        lsum[r] *= alpha;
#pragma unroll
        for (int dt = 0; dt < 4; ++dt) acco[dt][r] *= alpha;
      }
    }
#pragma unroll
    for (int r = 0; r < 4; ++r) {
      float rs = 0.f;
#pragma unroll
      for (int t = 0; t < 4; ++t) {
        float pv = __expf(s[t][r] - mrow[r]);   // bounded by e^8
        s[t][r] = pv;
        rs += pv;
      }
      rs += __shfl_xor(rs, 1, 64);
      rs += __shfl_xor(rs, 2, 64);
      rs += __shfl_xor(rs, 4, 64);
      rs += __shfl_xor(rs, 8, 64);
      lsum[r] += rs;
    }
#pragma unroll
    for (int t = 0; t < 4; ++t)
#pragma unroll
      for (int r = 0; r < 4; ++r)
        Ps[w][lg * 4 + r][t * 16 + lr] = f2bf(s[t][r]);
#pragma unroll
    for (int ks = 0; ks < 2; ++ks) {
      bf16x8 ap = *(const bf16x8*)&Ps[w][lr][ks * 32 + lg * 8];
#pragma unroll
      for (int dt = 0; dt < 4; ++dt) {
        const int vrow = dt * 16 + lr;
        bf16x8 bv = *(const bf16x8*)&Vs[p][vrow * 64 + ((ks * 4 + lg) ^ (lr & 7)) * 8];
        acco[dt] = __builtin_amdgcn_mfma_f32_16x16x32_bf16(ap, bv, acco[dt], 0, 0, 0);
      }
    }
    if (more) {
      asm volatile("s_waitcnt vmcnt(0)" ::: "memory");  // next tile landed
      __builtin_amdgcn_s_barrier();                     // all waves done with buf p
      fence_mem();
    }
  }

#pragma unroll
  for (int r = 0; r < 4; ++r) {
    const int qr = q0 + lg * 4 + r;
    const int nf = b * Nseq + qr;
    const float gate = gm[(size_t)nf * 32 + h];
    const float inv = 1.0f / lsum[r];
#pragma unroll
    for (int dt = 0; dt < 4; ++dt)
      attn_out[(size_t)nf * Dm + h * DH + dt * 16 + lr] = f2bf(acco[dt][r] * inv * gate);
  }
}

// ---------------- host launch ----------------
extern "C" void kernel_launch(void* const* d_in, const int* in_sizes, int n_in,
                              void* d_out, int out_size, void* d_ws, size_t ws_size,
                              hipStream_t stream) {
  const float* x_in  = (const float*)d_in[0];
  const float* naw   = (const float*)d_in[1];
  const float* wq    = (const float*)d_in[2];
  const float* wkv   = (const float*)d_in[3];
  const float* wo    = (const float*)d_in[4];
  const float* wg    = (const float*)d_in[5];
  const float* wmix  = (const float*)d_in[6];
  const float* nfw   = (const float*)d_in[7];
  const float* ffw   = (const float*)d_in[8];
  const float* w_in  = (const float*)d_in[9];
  const float* b_in  = (const float*)d_in[10];
  const float* w_out = (const float*)d_in[11];
  const float* b_out = (const float*)d_in[12];
  const float* fnw   = (const float*)d_in[13];

  uint8_t* ws = (uint8_t*)d_ws;
  size_t off = 0;
  auto alloc = [&](size_t bytes) -> void* {
    void* p = ws + off;
    off += (bytes + 255) & ~(size_t)255;
    return p;
  };
  float*          x_res    = (float*)alloc((size_t)ROWS * Dm * 4);
  unsigned short* h        = (unsigned short*)alloc((size_t)ROWS * Dm * 2);
  unsigned short* qkv_lin  = (unsigned short*)alloc((size_t)ROWS * 3072 * 2);
  float*          gm       = (float*)alloc((size_t)ROWS * 32 * 4);
  unsigned short* qb       = (unsigned short*)alloc((size_t)64 * Nseq * DH * 2);
  unsigned short* kb       = (unsigned short*)alloc((size_t)64 * Nseq * DH * 2);
  unsigned short* vtb      = (unsigned short*)alloc((size_t)64 * Nseq * DH * 2);
  unsigned short* vres     = (unsigned short*)alloc((size_t)64 * Nseq * DH * 2);
  unsigned short* attn     = (unsigned short*)alloc((size_t)ROWS * Dm * 2);
  float*          cost     = (float*)alloc((size_t)Nseq * 32 * 4);
  float*          sint     = (float*)alloc((size_t)Nseq * 32 * 4);
  unsigned short* wqkv_bf  = (unsigned short*)alloc((size_t)3072 * 1024 * 2);
  unsigned short* wo_bf    = (unsigned short*)alloc((size_t)1024 * 1024 * 2);
  unsigned short* wgm_bf   = (unsigned short*)alloc((size_t)128 * 1024 * 2);
  unsigned short* win_bf   = (unsigned short*)alloc((size_t)WIDE * 1024 * 2);  // 16-row groups
  unsigned short* wout_bf  = (unsigned short*)alloc((size_t)1024 * FI_PAD * 2);
  unsigned short* u = qkv_lin;  // alias: qkv scratch dead before FF uses u

  hipMemcpyAsync(x_res, x_in, (size_t)ROWS * Dm * 4, hipMemcpyDeviceToDevice, stream);
  rope_tables<<<128, 256, 0, stream>>>(cost, sint);

  for (int i = 0; i < NDEPTH; ++i) {
    convf2b<<<dim3(1, 1024), 128, 0, stream>>>(wq + (size_t)i * 1024 * 1024, wqkv_bf, 1024, 1024, 1024);
    convf2b<<<dim3(1, 2048), 128, 0, stream>>>(wkv + (size_t)i * 2048 * 1024, wqkv_bf + (size_t)1024 * 1024, 2048, 1024, 1024);
    convf2b<<<dim3(1, 1024), 128, 0, stream>>>(wo + (size_t)i * 1024 * 1024, wo_bf, 1024, 1024, 1024);
    convf2b<<<dim3(1, 16), 128, 0, stream>>>(wg + (size_t)i * 16 * 1024, wgm_bf, 16, 1024, 1024);
    convf2b<<<dim3(1, 16), 128, 0, stream>>>(wmix + (size_t)i * 16 * 1024, wgm_bf + 16 * 1024, 16, 1024, 1024);
    convf2b<<<dim3(1, 96), 128, 0, stream>>>(wg, wgm_bf + 32 * 1024, 0, 1024, 1024);  // zero rows 32..127
    convf2b_g16<<<dim3(1, WIDE), 128, 0, stream>>>(w_in + (size_t)i * 2 * FI * 1024, win_bf);
    convf2b<<<dim3(2, 1024), 256, 0, stream>>>(w_out + (size_t)i * 1024 * FI, wout_bf, 1024, FI, FI_PAD);

    rms_one<<<ROWS, 256, 0, stream>>>(x_res, naw + i * 1024, h);
    gemm_nt256<0><<<192, 512, 0, stream>>>(h, wqkv_bf, qkv_lin, nullptr, 1024, 3072, 16, 12);
    gemm_nt<1><<<dim3(32, 1), 256, 0, stream>>>(h, wgm_bf, gm, nullptr, nullptr, 1024, 32, 32);
    rope_qk<<<dim3(16, 64), 256, 0, stream>>>(qkv_lin, cost, sint, qb, kb);
    v_mix_pack<<<dim3(16, 64), 256, 0, stream>>>(qkv_lin, gm, vres, vtb, i);
    attn_fwd<<<1024, 256, 0, stream>>>(qb, kb, vtb, gm, attn);
    gemm_nt<2><<<dim3(32, 8), 256, 0, stream>>>(attn, wo_bf, x_res, nullptr, x_res, 1024, 1024, 1024);
    rms_ff<<<ROWS, 256, 0, stream>>>(x_res, nfw + i * 1024, ffw + i * 1024, h);
    gemm_nt256<3><<<352, 512, 0, stream>>>(h, win_bf, u, b_in + (size_t)i * 2 * FI, 1024, FI_PAD, 16, 22);
    gemm_nt<2><<<dim3(32, 8), 256, 0, stream>>>(u, wout_bf, x_res, b_out + i * 1024, x_res, FI_PAD, 1024, 1024);
  }
  rms_final<<<ROWS, 256, 0, stream>>>(x_res, fnw, (float*)d_out);
}

// Round 17
// 1299.694 us; speedup vs baseline: 1.0778x; 1.0237x over previous
//
#include <hip/hip_runtime.h>
#include <cstdint>
#include <cstddef>

// TransformerXL forward (B=4,N=1024,D=1024,H=16,DH=64,DEPTH=4, GEGLU FI=2730)
// R17: base = R16 (best, 1330us). GEGLU GEMM re-tiled 256x256 -> 128x256
//      (704 blocks vs 352): fixes grid-tail quantization (352 = 1.375 rounds
//      at 1 block/CU => 69% util; 704 = 2.75 rounds => ~92%).

#define DEV_INLINE __device__ __forceinline__

typedef short bf16x8 __attribute__((ext_vector_type(8)));
typedef float f32x4 __attribute__((ext_vector_type(4)));

constexpr int Bsz = 4, Nseq = 1024, Dm = 1024, Hh = 16, DH = 64, NDEPTH = 4;
constexpr int FI = 2730;        // GEGLU inner dim
constexpr int FI_PAD = 2752;    // u cols padded to /64 (zero-filled)
constexpr int FI_TILE = 2816;   // per-half weight rows padded to /128
constexpr int WIDE = 2 * FI_TILE;  // 5632: 16-row groups [16a | 16g | ...]
constexpr int ROWS = Bsz * Nseq; // 4096
constexpr float EPSR = 1.1920929e-07f;

DEV_INLINE float bf2f(unsigned short u) {
  unsigned int x = ((unsigned int)u) << 16;
  float f; __builtin_memcpy(&f, &x, 4); return f;
}
DEV_INLINE unsigned short f2bf(float f) {
  unsigned int x; __builtin_memcpy(&x, &f, 4);
  unsigned int r = x + 0x7fffu + ((x >> 16) & 1u);  // RNE
  return (unsigned short)(r >> 16);
}

using gptr_t = const __attribute__((address_space(1))) void*;
using lptr_t = __attribute__((address_space(3))) void*;
DEV_INLINE void gl_lds16(const void* g, void* l) {
  __builtin_amdgcn_global_load_lds((gptr_t)g, (lptr_t)l, 16, 0, 0);
}
DEV_INLINE void fence_mem() { asm volatile("" ::: "memory"); }

// ---------------- weight fp32 -> bf16 (vectorized, with zero padding) -----------
__global__ __launch_bounds__(256)
void convf2b(const float* __restrict__ src, unsigned short* __restrict__ dst,
             int src_rows, int src_cols, int dst_cols) {
  const int r = blockIdx.y;
  const int c8 = (blockIdx.x * blockDim.x + threadIdx.x) * 8;
  if (c8 >= dst_cols) return;
  alignas(16) unsigned short o[8];
  if (r < src_rows && c8 + 8 <= src_cols) {
    const float2* p = (const float2*)&src[(size_t)r * src_cols + c8];
    const float2 v0 = p[0], v1 = p[1], v2 = p[2], v3 = p[3];
    o[0] = f2bf(v0.x); o[1] = f2bf(v0.y); o[2] = f2bf(v1.x); o[3] = f2bf(v1.y);
    o[4] = f2bf(v2.x); o[5] = f2bf(v2.y); o[6] = f2bf(v3.x); o[7] = f2bf(v3.y);
  } else {
#pragma unroll
    for (int j = 0; j < 8; ++j) {
      const int c = c8 + j;
      float v = (r < src_rows && c < src_cols) ? src[(size_t)r * src_cols + c] : 0.0f;
      o[j] = f2bf(v);
    }
  }
  *(uint4*)&dst[(size_t)r * dst_cols + c8] = *(const uint4*)o;
}

// w_in 16-row-group interleave: dst rows [32t..32t+16) = a[16t..), [+16..32) = g
__global__ __launch_bounds__(128)
void convf2b_g16(const float* __restrict__ src, unsigned short* __restrict__ dst) {
  const int p = blockIdx.y;           // 0..WIDE-1
  const int c8 = threadIdx.x * 8;     // 128 thr * 8 = 1024 cols
  const int t = p >> 5, r5 = p & 31;
  const int srow = t * 16 + (r5 & 15);
  alignas(16) unsigned short o[8];
  if (srow < FI) {
    const size_t base = ((size_t)((r5 < 16) ? 0 : 1) * FI + srow) * 1024 + c8;
    const float4 v0 = *(const float4*)&src[base];
    const float4 v1 = *(const float4*)&src[base + 4];
    o[0]=f2bf(v0.x); o[1]=f2bf(v0.y); o[2]=f2bf(v0.z); o[3]=f2bf(v0.w);
    o[4]=f2bf(v1.x); o[5]=f2bf(v1.y); o[6]=f2bf(v1.z); o[7]=f2bf(v1.w);
  } else {
#pragma unroll
    for (int j = 0; j < 8; ++j) o[j] = 0;
  }
  *(uint4*)&dst[(size_t)p * 1024 + c8] = *(const uint4*)o;
}

// ---------------- rope cos/sin tables ----------------
__global__ __launch_bounds__(256)
void rope_tables(float* __restrict__ cost, float* __restrict__ sint) {
  int idx = blockIdx.x * 256 + threadIdx.x;
  if (idx >= Nseq * 32) return;
  int n = idx >> 5, p = idx & 31;
  float freq = powf(10000.0f, -(float)(2 * p) * (1.0f / 64.0f));
  float ang = (float)n * freq;
  cost[idx] = cosf(ang);
  sint[idx] = sinf(ang);
}

// ---------------- RMSNorm variants ----------------
__global__ __launch_bounds__(256)
void rms_one(const float* __restrict__ x, const float* __restrict__ w,
             unsigned short* __restrict__ out) {
  __shared__ float sred[4];
  const int row = blockIdx.x, tid = threadIdx.x;
  const float4 v = ((const float4*)(x + (size_t)row * Dm))[tid];
  float ss = v.x * v.x + v.y * v.y + v.z * v.z + v.w * v.w;
#pragma unroll
  for (int o = 32; o >= 1; o >>= 1) ss += __shfl_xor(ss, o, 64);
  if ((tid & 63) == 0) sred[tid >> 6] = ss;
  __syncthreads();
  float rs = rsqrtf((sred[0] + sred[1] + sred[2] + sred[3]) * (1.0f / Dm) + EPSR);
  const float4 wv = ((const float4*)w)[tid];
  alignas(8) unsigned short o4[4] = { f2bf(v.x * rs * wv.x), f2bf(v.y * rs * wv.y),
                                      f2bf(v.z * rs * wv.z), f2bf(v.w * rs * wv.w) };
  *(uint2*)&out[(size_t)row * Dm + tid * 4] = *(const uint2*)o4;
}

__global__ __launch_bounds__(256)
void rms_ff(const float* __restrict__ x, const float* __restrict__ w1,
            const float* __restrict__ w2, unsigned short* __restrict__ out) {
  __shared__ float sred[4];
  const int row = blockIdx.x, tid = threadIdx.x;
  const float4 v = ((const float4*)(x + (size_t)row * Dm))[tid];
  const float4 w1v = ((const float4*)w1)[tid];
  const float4 w2v = ((const float4*)w2)[tid];
  float ss = v.x * v.x + v.y * v.y + v.z * v.z + v.w * v.w;
#pragma unroll
  for (int o = 32; o >= 1; o >>= 1) ss += __shfl_xor(ss, o, 64);
  if ((tid & 63) == 0) sred[tid >> 6] = ss;
  __syncthreads();
  float rs1 = rsqrtf((sred[0] + sred[1] + sred[2] + sred[3]) * (1.0f / Dm) + EPSR);
  float t0 = v.x * rs1 * w1v.x, t1 = v.y * rs1 * w1v.y;
  float t2 = v.z * rs1 * w1v.z, t3 = v.w * rs1 * w1v.w;
  float ss2 = t0 * t0 + t1 * t1 + t2 * t2 + t3 * t3;
#pragma unroll
  for (int o = 32; o >= 1; o >>= 1) ss2 += __shfl_xor(ss2, o, 64);
  __syncthreads();
  if ((tid & 63) == 0) sred[tid >> 6] = ss2;
  __syncthreads();
  float rs2 = rsqrtf((sred[0] + sred[1] + sred[2] + sred[3]) * (1.0f / Dm) + EPSR);
  alignas(8) unsigned short o4[4] = { f2bf(t0 * rs2 * w2v.x), f2bf(t1 * rs2 * w2v.y),
                                      f2bf(t2 * rs2 * w2v.z), f2bf(t3 * rs2 * w2v.w) };
  *(uint2*)&out[(size_t)row * Dm + tid * 4] = *(const uint2*)o4;
}

__global__ __launch_bounds__(256)
void rms_final(const float* __restrict__ x, const float* __restrict__ w,
               float* __restrict__ out) {
  __shared__ float sred[4];
  const int row = blockIdx.x, tid = threadIdx.x;
  const float4 v = ((const float4*)(x + (size_t)row * Dm))[tid];
  float ss = v.x * v.x + v.y * v.y + v.z * v.z + v.w * v.w;
#pragma unroll
  for (int o = 32; o >= 1; o >>= 1) ss += __shfl_xor(ss, o, 64);
  if ((tid & 63) == 0) sred[tid >> 6] = ss;
  __syncthreads();
  float rs = rsqrtf((sred[0] + sred[1] + sred[2] + sred[3]) * (1.0f / Dm) + EPSR);
  const float4 wv = ((const float4*)w)[tid];
  float4 o;
  o.x = v.x * rs * wv.x; o.y = v.y * rs * wv.y;
  o.z = v.z * rs * wv.z; o.w = v.w * rs * wv.w;
  ((float4*)(out + (size_t)row * Dm))[tid] = o;
}

// ---------------- 128x128 NT GEMM (R9 schedule) ----------------
// MODE: 1=sigmoid f32, 2=f32 residual(+bias)
template <int MODE>
__global__ __launch_bounds__(256)
void gemm_nt(const unsigned short* __restrict__ A,
             const unsigned short* __restrict__ Bw,
             void* __restrict__ Cout,
             const float* __restrict__ bias,
             const float* __restrict__ resid,
             int K, int ldc, int n_store) {
  __shared__ unsigned short As[2][128 * 64];
  __shared__ unsigned short Bs[2][128 * 64];
  const int tid = threadIdx.x;
  const int m0 = blockIdx.x * 128;
  const int n0 = blockIdx.y * 128;
  const int w = tid >> 6, l = tid & 63;
  const int wm = (w >> 1) * 64, wn = (w & 1) * 64;
  const int lr = l & 15, lg = l >> 4;
  const int lsub = l & 7, lrow8 = l >> 3;
  const int colsw = (lsub ^ lrow8) << 3;
  const unsigned short* gA = &A[(size_t)(m0 + w * 8 + lrow8) * K + colsw];
  const unsigned short* gB = &Bw[(size_t)(n0 + w * 8 + lrow8) * K + colsw];
  const size_t rstep = (size_t)32 * K;
  f32x4 acc[4][4] = {};

  auto stage = [&](int buf, int kt) {
    const int o = kt * 64;
#pragma unroll
    for (int i = 0; i < 4; ++i) {
      gl_lds16(gA + i * rstep + o, &As[buf][i * 2048 + w * 512]);
      gl_lds16(gB + i * rstep + o, &Bs[buf][i * 2048 + w * 512]);
    }
  };
  auto compute = [&](int buf) {
    bf16x8 af[2][4], bfr[2][4];
#pragma unroll
    for (int ks = 0; ks < 2; ++ks) {
      const int slot = (ks * 4 + lg) ^ (lr & 7);
#pragma unroll
      for (int fj = 0; fj < 4; ++fj)
        bfr[ks][fj] = *(const bf16x8*)&Bs[buf][(wn + fj * 16 + lr) * 64 + slot * 8];
#pragma unroll
      for (int fi = 0; fi < 4; ++fi)
        af[ks][fi] = *(const bf16x8*)&As[buf][(wm + fi * 16 + lr) * 64 + slot * 8];
    }
    __builtin_amdgcn_s_setprio(1);
#pragma unroll
    for (int ks = 0; ks < 2; ++ks)
#pragma unroll
      for (int fi = 0; fi < 4; ++fi)
#pragma unroll
        for (int fj = 0; fj < 4; ++fj)
          acc[fi][fj] = __builtin_amdgcn_mfma_f32_16x16x32_bf16(af[ks][fi], bfr[ks][fj], acc[fi][fj], 0, 0, 0);
    __builtin_amdgcn_s_setprio(0);
  };

  const int nk = K >> 6;
  stage(0, 0);
  asm volatile("s_waitcnt vmcnt(0)" ::: "memory");
  __builtin_amdgcn_s_barrier();
  fence_mem();
  int cur = 0;
#pragma unroll 1
  for (int kt = 0; kt < nk; ++kt) {
    const bool more = (kt + 1 < nk);
    if (more) stage(cur ^ 1, kt + 1);
    compute(cur);
    if (more) {
      asm volatile("s_waitcnt vmcnt(0)" ::: "memory");
      __builtin_amdgcn_s_barrier();
      fence_mem();
    }
    cur ^= 1;
  }

#pragma unroll
  for (int fi = 0; fi < 4; ++fi) {
    const int rowb = m0 + wm + fi * 16 + lg * 4;
#pragma unroll
    for (int fj = 0; fj < 4; ++fj) {
      const int col = n0 + wn + fj * 16 + lr;
#pragma unroll
      for (int r = 0; r < 4; ++r) {
        const float val = acc[fi][fj][r];
        const int rr = rowb + r;
        if constexpr (MODE == 1) {
          if (col < n_store)
            ((float*)Cout)[(size_t)rr * ldc + col] = 1.0f / (1.0f + __expf(-val));
        } else {  // MODE 2
          const float bv = bias ? bias[col] : 0.0f;
          ((float*)Cout)[(size_t)rr * ldc + col] =
              resid[(size_t)rr * ldc + col] + val + bv;
        }
      }
    }
  }
}

// ---------------- 256x256 NT GEMM: 512 thr, 8 waves (2Mx4N), BK=64 ----------------
// (qkv only now.) 4 stage-parts per K-tile; no intra-tile barriers; tile-end
// vmcnt(0)+barrier. XCD swizzle. MODE 0 = bf16 store.
template <int MODE>
__global__ __launch_bounds__(512, 2)
void gemm_nt256(const unsigned short* __restrict__ A,
                const unsigned short* __restrict__ Bw,
                void* __restrict__ Cout,
                const float* __restrict__ bias,
                int K, int ldc, int nm, int nn) {
  __shared__ unsigned short As[2][256 * 64];
  __shared__ unsigned short Bs[2][256 * 64];
  const int tid = threadIdx.x;
  const int nwg = nm * nn;
  const int qq = nwg >> 3;
  const int xcd = blockIdx.x & 7, orig = blockIdx.x >> 3;
  const int wgid = xcd * qq + orig;
  const int m0 = (wgid % nm) * 256;
  const int n0 = (wgid / nm) * 256;
  const int w = tid >> 6, l = tid & 63;
  const int wm = (w >> 2) * 128, wn = (w & 3) * 64;
  const int lr = l & 15, lg = l >> 4;
  const int lsub = l & 7, lrow8 = l >> 3;
  const int colsw = (lsub ^ lrow8) << 3;
  const unsigned short* gA = &A[(size_t)(m0 + w * 8 + lrow8) * K + colsw];
  const unsigned short* gB = &Bw[(size_t)(n0 + w * 8 + lrow8) * K + colsw];
  const size_t rstep = (size_t)64 * K;
  f32x4 acc[8][4] = {};

  auto stage_part = [&](int buf, int kt, int part) {
    const int o = kt * 64;
    const int i0 = (part & 1) * 2;
    if (part < 2) {
      gl_lds16(gA + (size_t)i0 * rstep + o,       &As[buf][i0 * 4096 + w * 512]);
      gl_lds16(gA + (size_t)(i0 + 1) * rstep + o, &As[buf][(i0 + 1) * 4096 + w * 512]);
    } else {
      gl_lds16(gB + (size_t)i0 * rstep + o,       &Bs[buf][i0 * 4096 + w * 512]);
      gl_lds16(gB + (size_t)(i0 + 1) * rstep + o, &Bs[buf][(i0 + 1) * 4096 + w * 512]);
    }
  };

  const int nk = K >> 6;
  stage_part(0, 0, 0); stage_part(0, 0, 1);
  stage_part(0, 0, 2); stage_part(0, 0, 3);
  asm volatile("s_waitcnt vmcnt(0)" ::: "memory");
  __builtin_amdgcn_s_barrier();
  fence_mem();

#pragma unroll 1
  for (int t = 0; t < nk; ++t) {
    const int p = t & 1;
    const bool more = (t + 1 < nk);
    bf16x8 bfr[4];
#pragma unroll
    for (int q = 0; q < 4; ++q) {
      const int ks = q >> 1, half = q & 1;
      const int slot = (ks * 4 + lg) ^ (lr & 7);
      if (half == 0) {
#pragma unroll
        for (int fj = 0; fj < 4; ++fj)
          bfr[fj] = *(const bf16x8*)&Bs[p][(wn + fj * 16 + lr) * 64 + slot * 8];
      }
      bf16x8 af[4];
#pragma unroll
      for (int fi = 0; fi < 4; ++fi)
        af[fi] = *(const bf16x8*)&As[p][(wm + half * 64 + fi * 16 + lr) * 64 + slot * 8];
      if (more) stage_part(p ^ 1, t + 1, q);
      __builtin_amdgcn_s_setprio(1);
#pragma unroll
      for (int fi = 0; fi < 4; ++fi)
#pragma unroll
        for (int fj = 0; fj < 4; ++fj)
          acc[half * 4 + fi][fj] =
              __builtin_amdgcn_mfma_f32_16x16x32_bf16(af[fi], bfr[fj], acc[half * 4 + fi][fj], 0, 0, 0);
      __builtin_amdgcn_s_setprio(0);
    }
    if (more) {
      asm volatile("s_waitcnt vmcnt(0)" ::: "memory");
      __builtin_amdgcn_s_barrier();
      fence_mem();
    }
  }

#pragma unroll
  for (int fi = 0; fi < 8; ++fi) {
    const int rowb = m0 + wm + fi * 16 + lg * 4;
#pragma unroll
    for (int fj = 0; fj < 4; ++fj) {
      const int col = n0 + wn + fj * 16 + lr;
#pragma unroll
      for (int r = 0; r < 4; ++r)
        ((unsigned short*)Cout)[(size_t)(rowb + r) * ldc + col] = f2bf(acc[fi][fj][r]);
    }
  }
}

// ---------------- 128x256 NT GEMM (GEGLU): 512 thr, 8 waves (2Mx4N) ----------------
// BM=128 (wave owns 64 rows), BN=256; LDS 96KB; 704-block grid (tail-balanced).
// Same 2-phase schedule + involution swizzle; grouped-GEGLU epilogue.
__global__ __launch_bounds__(512, 2)
void gemm_geglu128(const unsigned short* __restrict__ A,
                   const unsigned short* __restrict__ Bw,
                   unsigned short* __restrict__ Cout,
                   const float* __restrict__ bias,
                   int K, int ldc, int nm, int nn) {
  __shared__ unsigned short As[2][128 * 64];   // 16 KB each
  __shared__ unsigned short Bs[2][256 * 64];   // 32 KB each
  const int tid = threadIdx.x;
  const int nwg = nm * nn;
  const int qq = nwg >> 3;
  const int xcd = blockIdx.x & 7, orig = blockIdx.x >> 3;
  const int wgid = xcd * qq + orig;
  const int m0 = (wgid % nm) * 128;
  const int n0 = (wgid / nm) * 256;
  const int w = tid >> 6, l = tid & 63;
  const int wm = (w >> 2) * 64, wn = (w & 3) * 64;   // wave: 64x64
  const int lr = l & 15, lg = l >> 4;
  const int lsub = l & 7, lrow8 = l >> 3;
  const int colsw = (lsub ^ lrow8) << 3;
  const unsigned short* gA = &A[(size_t)(m0 + w * 8 + lrow8) * K + colsw];
  const unsigned short* gB = &Bw[(size_t)(n0 + w * 8 + lrow8) * K + colsw];
  const size_t rstep = (size_t)64 * K;   // 512 lanes x 8 els = 64 rows / instr
  f32x4 acc[4][4] = {};

  auto stage = [&](int buf, int kt) {
    const int o = kt * 64;
#pragma unroll
    for (int i = 0; i < 2; ++i)
      gl_lds16(gA + (size_t)i * rstep + o, &As[buf][i * 4096 + w * 512]);
#pragma unroll
    for (int i = 0; i < 4; ++i)
      gl_lds16(gB + (size_t)i * rstep + o, &Bs[buf][i * 4096 + w * 512]);
  };
  auto compute = [&](int buf) {
#pragma unroll
    for (int ks = 0; ks < 2; ++ks) {
      const int slot = (ks * 4 + lg) ^ (lr & 7);
      bf16x8 bfr[4], af[4];
#pragma unroll
      for (int fj = 0; fj < 4; ++fj)
        bfr[fj] = *(const bf16x8*)&Bs[buf][(wn + fj * 16 + lr) * 64 + slot * 8];
#pragma unroll
      for (int fi = 0; fi < 4; ++fi)
        af[fi] = *(const bf16x8*)&As[buf][(wm + fi * 16 + lr) * 64 + slot * 8];
      __builtin_amdgcn_s_setprio(1);
#pragma unroll
      for (int fi = 0; fi < 4; ++fi)
#pragma unroll
        for (int fj = 0; fj < 4; ++fj)
          acc[fi][fj] = __builtin_amdgcn_mfma_f32_16x16x32_bf16(af[fi], bfr[fj], acc[fi][fj], 0, 0, 0);
      __builtin_amdgcn_s_setprio(0);
    }
  };

  const int nk = K >> 6;
  stage(0, 0);
  asm volatile("s_waitcnt vmcnt(0)" ::: "memory");
  __builtin_amdgcn_s_barrier();
  fence_mem();
  int cur = 0;
#pragma unroll 1
  for (int kt = 0; kt < nk; ++kt) {
    const bool more = (kt + 1 < nk);
    if (more) stage(cur ^ 1, kt + 1);
    compute(cur);
    if (more) {
      asm volatile("s_waitcnt vmcnt(0)" ::: "memory");
      __builtin_amdgcn_s_barrier();
      fence_mem();
    }
    cur ^= 1;
  }

  // grouped-GEGLU epilogue: cols in 16-groups [a|g]; pair (2fjp, 2fjp+1) in-thread
#pragma unroll
  for (int fi = 0; fi < 4; ++fi) {
    const int rowb = m0 + wm + fi * 16 + lg * 4;
#pragma unroll
    for (int fjp = 0; fjp < 2; ++fjp) {
      const int ucol = ((n0 + wn) >> 1) + fjp * 16 + lr;
      if (ucol >= FI_PAD) continue;
      const bool live = (ucol < FI);
      const float ba = live ? bias[ucol] : 0.0f;
      const float bg = live ? bias[FI + ucol] : 0.0f;
#pragma unroll
      for (int r = 0; r < 4; ++r) {
        const float va = acc[fi][2 * fjp][r] + ba;
        const float vg = acc[fi][2 * fjp + 1][r] + bg;
        const float gel = 0.5f * vg * (1.0f + erff(vg * 0.70710678118654752f));
        Cout[(size_t)(rowb + r) * ldc + ucol] = f2bf(live ? va * gel : 0.0f);
      }
    }
  }
}

// ---------------- RoPE on q,k (q also * DH^-0.5) ----------------
__global__ __launch_bounds__(256)
void rope_qk(const unsigned short* __restrict__ qkv_lin,
             const float* __restrict__ cost, const float* __restrict__ sint,
             unsigned short* __restrict__ qb, unsigned short* __restrict__ kb) {
  const int nt = blockIdx.x, bh = blockIdx.y;
  const int b = bh >> 4, h = bh & 15;
  const int tid = threadIdx.x;
  const int pi = tid & 31, r0 = tid >> 5;
  const float scale = 0.125f;
#pragma unroll
  for (int j = 0; j < 8; ++j) {
    const int n = nt * 64 + r0 + j * 8;
    const int nf = b * Nseq + n;
    const float c = cost[n * 32 + pi], s = sint[n * 32 + pi];
    const unsigned short* qp = &qkv_lin[(size_t)nf * 3072 + h * 64 + pi * 2];
    float q0 = bf2f(qp[0]), q1 = bf2f(qp[1]);
    alignas(4) unsigned short oq[2];
    oq[0] = f2bf((q0 * c - q1 * s) * scale);
    oq[1] = f2bf((q1 * c + q0 * s) * scale);
    *(unsigned int*)&qb[((size_t)bh * Nseq + n) * 64 + pi * 2] = *(const unsigned int*)oq;
    const unsigned short* kp = &qkv_lin[(size_t)nf * 3072 + 1024 + h * 64 + pi * 2];
    float k0 = bf2f(kp[0]), k1 = bf2f(kp[1]);
    alignas(4) unsigned short ok[2];
    ok[0] = f2bf(k0 * c - k1 * s);
    ok[1] = f2bf(k1 * c + k0 * s);
    *(unsigned int*)&kb[((size_t)bh * Nseq + n) * 64 + pi * 2] = *(const unsigned int*)ok;
  }
}

// ---------------- v: value-residual lerp + transpose-pack ----------------
__global__ __launch_bounds__(256)
void v_mix_pack(const unsigned short* __restrict__ qkv_lin,
                const float* __restrict__ gm,
                unsigned short* __restrict__ vres,
                unsigned short* __restrict__ vtb, int layer) {
  __shared__ unsigned short T[64][72];
  const int nt = blockIdx.x, bh = blockIdx.y;
  const int b = bh >> 4, h = bh & 15;
  const int tid = threadIdx.x;
#pragma unroll
  for (int p = 0; p < 2; ++p) {
    int c = tid + p * 256;
    int nl = c >> 3, cg = (c & 7) << 3;
    int n = nt * 64 + nl, nf = b * Nseq + n;
    uint4 vv = *(const uint4*)&qkv_lin[(size_t)nf * 3072 + 2048 + h * 64 + cg];
    if (layer == 0) {
      *(uint4*)&vres[((size_t)bh * Nseq + n) * 64 + cg] = vv;
      *(uint4*)&T[nl][cg] = vv;
    } else {
      alignas(16) unsigned short ve[8]; *(uint4*)ve = vv;
      uint4 rv = *(const uint4*)&vres[((size_t)bh * Nseq + n) * 64 + cg];
      alignas(16) unsigned short re[8]; *(uint4*)re = rv;
      const float mix = gm[(size_t)nf * 32 + 16 + h];
      alignas(16) unsigned short oe[8];
#pragma unroll
      for (int j = 0; j < 8; ++j) {
        float v = bf2f(ve[j]), rr = bf2f(re[j]);
        oe[j] = f2bf(v + mix * (rr - v));
      }
      *(uint4*)&T[nl][cg] = *(const uint4*)oe;
    }
  }
  __syncthreads();
#pragma unroll
  for (int p = 0; p < 2; ++p) {
    int c = tid + p * 256;
    int d = c >> 3, ng = (c & 7) << 3;
    alignas(16) unsigned short oe[8];
#pragma unroll
    for (int j = 0; j < 8; ++j) oe[j] = T[ng + j][d];
    *(uint4*)&vtb[(size_t)bh * 65536 + (size_t)d * Nseq + nt * 64 + ng] = *(const uint4*)oe;
  }
}

// ---------------- causal flash attention + gate + head-merge ----------------
__global__ __launch_bounds__(256)
void attn_fwd(const unsigned short* __restrict__ qb,
              const unsigned short* __restrict__ kb,
              const unsigned short* __restrict__ vtb,
              const float* __restrict__ gm,
              unsigned short* __restrict__ attn_out) {
  __shared__ unsigned short Ks[2][64 * 64];   // [key][dh], swizzled
  __shared__ unsigned short Vs[2][64 * 64];   // V^T: [dh][key], swizzled
  __shared__ unsigned short Ps[4][16][72];
  const int bid = blockIdx.x;
  const int x = bid & 7, rest = bid >> 3;
  const int bh = x * 8 + (rest & 7);
  const int qt = 15 - (rest >> 3);
  const int b = bh >> 4, h = bh & 15;
  const int tid = threadIdx.x;
  const int w = tid >> 6, l = tid & 63;
  const int lr = l & 15, lg = l >> 4;
  const int q0 = qt * 64 + w * 16;
  const size_t head = (size_t)bh * Nseq * DH;
  const int lrow8 = l >> 3;
  const int colsw = ((l & 7) ^ lrow8) << 3;

  auto stageKV = [&](int buf, int kt) {
    const int kv0 = kt * 64;
#pragma unroll
    for (int i = 0; i < 2; ++i) {
      const int rb = w * 16 + i * 8;
      gl_lds16(&kb[head + (size_t)(kv0 + rb + lrow8) * DH + colsw],
               &Ks[buf][rb * 64]);
      gl_lds16(&vtb[head + (size_t)(rb + lrow8) * Nseq + kv0 + colsw],
               &Vs[buf][rb * 64]);
    }
  };

  bf16x8 aq[2];
  aq[0] = *(const bf16x8*)&qb[head + (size_t)(q0 + lr) * DH + lg * 8];
  aq[1] = *(const bf16x8*)&qb[head + (size_t)(q0 + lr) * DH + 32 + lg * 8];

  float mrow[4] = {-1e30f, -1e30f, -1e30f, -1e30f};
  float lsum[4] = {0.f, 0.f, 0.f, 0.f};
  f32x4 acco[4] = {};

  stageKV(0, 0);
  asm volatile("s_waitcnt vmcnt(0)" ::: "memory");
  __builtin_amdgcn_s_barrier();
  fence_mem();

#pragma unroll 1
  for (int kt = 0; kt <= qt; ++kt) {
    const int p = kt & 1;
    const int kv0 = kt * 64;
    const bool more = (kt < qt);
    if (more) stageKV(p ^ 1, kt + 1);      // async prefetch next K/V tile
    f32x4 s[4];
#pragma unroll
    for (int t = 0; t < 4; ++t) {
      const int krow = t * 16 + lr;
      bf16x8 bk0 = *(const bf16x8*)&Ks[p][krow * 64 + ((0 + lg) ^ (lr & 7)) * 8];
      bf16x8 bk1 = *(const bf16x8*)&Ks[p][krow * 64 + ((4 + lg) ^ (lr & 7)) * 8];
      f32x4 z = {};
      z = __builtin_amdgcn_mfma_f32_16x16x32_bf16(aq[0], bk0, z, 0, 0, 0);
      z = __builtin_amdgcn_mfma_f32_16x16x32_bf16(aq[1], bk1, z, 0, 0, 0);
      s[t] = z;
    }
    const bool diag = (kt == qt);
    float mx4[4];
    bool need = false;
#pragma unroll
    for (int r = 0; r < 4; ++r) {
      const int qr = q0 + lg * 4 + r;
      float mx = -1e30f;
#pragma unroll
      for (int t = 0; t < 4; ++t) {
        float sv = s[t][r];
        if (diag && (kv0 + t * 16 + lr > qr)) sv = -1e30f;
        s[t][r] = sv;
        mx = fmaxf(mx, sv);
      }
      mx = fmaxf(mx, __shfl_xor(mx, 1, 64));
      mx = fmaxf(mx, __shfl_xor(mx, 2, 64));
      mx = fmaxf(mx, __shfl_xor(mx, 4, 64));
      mx = fmaxf(mx, __shfl_xor(mx, 8, 64));
      mx4[r] = mx;
      need = need || (mx > mrow[r] + 8.0f);
    }
    if (__any(need)) {    // defer-max
#pragma unroll
      for (int r = 0; r < 4; ++r) {
        const float mn = fmaxf(mrow[r], mx4[r]);
        const float alpha = __expf(mrow[r] - mn);
        mrow[r] = mn;
        lsum[r] *= alpha;
#pragma unroll
        for (int dt = 0; dt < 4; ++dt) acco[dt][r] *= alpha;
      }
    }
#pragma unroll
    for (int r = 0; r < 4; ++r) {
      float rs = 0.f;
#pragma unroll
      for (int t = 0; t < 4; ++t) {
        float pv = __expf(s[t][r] - mrow[r]);   // bounded by e^8
        s[t][r] = pv;
        rs += pv;
      }
      rs += __shfl_xor(rs, 1, 64);
      rs += __shfl_xor(rs, 2, 64);
      rs += __shfl_xor(rs, 4, 64);
      rs += __shfl_xor(rs, 8, 64);
      lsum[r] += rs;
    }
#pragma unroll
    for (int t = 0; t < 4; ++t)
#pragma unroll
      for (int r = 0; r < 4; ++r)
        Ps[w][lg * 4 + r][t * 16 + lr] = f2bf(s[t][r]);
#pragma unroll
    for (int ks = 0; ks < 2; ++ks) {
      bf16x8 ap = *(const bf16x8*)&Ps[w][lr][ks * 32 + lg * 8];
#pragma unroll
      for (int dt = 0; dt < 4; ++dt) {
        const int vrow = dt * 16 + lr;
        bf16x8 bv = *(const bf16x8*)&Vs[p][vrow * 64 + ((ks * 4 + lg) ^ (lr & 7)) * 8];
        acco[dt] = __builtin_amdgcn_mfma_f32_16x16x32_bf16(ap, bv, acco[dt], 0, 0, 0);
      }
    }
    if (more) {
      asm volatile("s_waitcnt vmcnt(0)" ::: "memory");  // next tile landed
      __builtin_amdgcn_s_barrier();                     // all waves done with buf p
      fence_mem();
    }
  }

#pragma unroll
  for (int r = 0; r < 4; ++r) {
    const int qr = q0 + lg * 4 + r;
    const int nf = b * Nseq + qr;
    const float gate = gm[(size_t)nf * 32 + h];
    const float inv = 1.0f / lsum[r];
#pragma unroll
    for (int dt = 0; dt < 4; ++dt)
      attn_out[(size_t)nf * Dm + h * DH + dt * 16 + lr] = f2bf(acco[dt][r] * inv * gate);
  }
}

// ---------------- host launch ----------------
extern "C" void kernel_launch(void* const* d_in, const int* in_sizes, int n_in,
                              void* d_out, int out_size, void* d_ws, size_t ws_size,
                              hipStream_t stream) {
  const float* x_in  = (const float*)d_in[0];
  const float* naw   = (const float*)d_in[1];
  const float* wq    = (const float*)d_in[2];
  const float* wkv   = (const float*)d_in[3];
  const float* wo    = (const float*)d_in[4];
  const float* wg    = (const float*)d_in[5];
  const float* wmix  = (const float*)d_in[6];
  const float* nfw   = (const float*)d_in[7];
  const float* ffw   = (const float*)d_in[8];
  const float* w_in  = (const float*)d_in[9];
  const float* b_in  = (const float*)d_in[10];
  const float* w_out = (const float*)d_in[11];
  const float* b_out = (const float*)d_in[12];
  const float* fnw   = (const float*)d_in[13];

  uint8_t* ws = (uint8_t*)d_ws;
  size_t off = 0;
  auto alloc = [&](size_t bytes) -> void* {
    void* p = ws + off;
    off += (bytes + 255) & ~(size_t)255;
    return p;
  };
  float*          x_res    = (float*)alloc((size_t)ROWS * Dm * 4);
  unsigned short* h        = (unsigned short*)alloc((size_t)ROWS * Dm * 2);
  unsigned short* qkv_lin  = (unsigned short*)alloc((size_t)ROWS * 3072 * 2);
  float*          gm       = (float*)alloc((size_t)ROWS * 32 * 4);
  unsigned short* qb       = (unsigned short*)alloc((size_t)64 * Nseq * DH * 2);
  unsigned short* kb       = (unsigned short*)alloc((size_t)64 * Nseq * DH * 2);
  unsigned short* vtb      = (unsigned short*)alloc((size_t)64 * Nseq * DH * 2);
  unsigned short* vres     = (unsigned short*)alloc((size_t)64 * Nseq * DH * 2);
  unsigned short* attn     = (unsigned short*)alloc((size_t)ROWS * Dm * 2);
  float*          cost     = (float*)alloc((size_t)Nseq * 32 * 4);
  float*          sint     = (float*)alloc((size_t)Nseq * 32 * 4);
  unsigned short* wqkv_bf  = (unsigned short*)alloc((size_t)3072 * 1024 * 2);
  unsigned short* wo_bf    = (unsigned short*)alloc((size_t)1024 * 1024 * 2);
  unsigned short* wgm_bf   = (unsigned short*)alloc((size_t)128 * 1024 * 2);
  unsigned short* win_bf   = (unsigned short*)alloc((size_t)WIDE * 1024 * 2);  // 16-row groups
  unsigned short* wout_bf  = (unsigned short*)alloc((size_t)1024 * FI_PAD * 2);
  unsigned short* u = qkv_lin;  // alias: qkv scratch dead before FF uses u

  hipMemcpyAsync(x_res, x_in, (size_t)ROWS * Dm * 4, hipMemcpyDeviceToDevice, stream);
  rope_tables<<<128, 256, 0, stream>>>(cost, sint);

  for (int i = 0; i < NDEPTH; ++i) {
    convf2b<<<dim3(1, 1024), 128, 0, stream>>>(wq + (size_t)i * 1024 * 1024, wqkv_bf, 1024, 1024, 1024);
    convf2b<<<dim3(1, 2048), 128, 0, stream>>>(wkv + (size_t)i * 2048 * 1024, wqkv_bf + (size_t)1024 * 1024, 2048, 1024, 1024);
    convf2b<<<dim3(1, 1024), 128, 0, stream>>>(wo + (size_t)i * 1024 * 1024, wo_bf, 1024, 1024, 1024);
    convf2b<<<dim3(1, 16), 128, 0, stream>>>(wg + (size_t)i * 16 * 1024, wgm_bf, 16, 1024, 1024);
    convf2b<<<dim3(1, 16), 128, 0, stream>>>(wmix + (size_t)i * 16 * 1024, wgm_bf + 16 * 1024, 16, 1024, 1024);
    convf2b<<<dim3(1, 96), 128, 0, stream>>>(wg, wgm_bf + 32 * 1024, 0, 1024, 1024);  // zero rows 32..127
    convf2b_g16<<<dim3(1, WIDE), 128, 0, stream>>>(w_in + (size_t)i * 2 * FI * 1024, win_bf);
    convf2b<<<dim3(2, 1024), 256, 0, stream>>>(w_out + (size_t)i * 1024 * FI, wout_bf, 1024, FI, FI_PAD);

    rms_one<<<ROWS, 256, 0, stream>>>(x_res, naw + i * 1024, h);
    gemm_nt256<0><<<192, 512, 0, stream>>>(h, wqkv_bf, qkv_lin, nullptr, 1024, 3072, 16, 12);
    gemm_nt<1><<<dim3(32, 1), 256, 0, stream>>>(h, wgm_bf, gm, nullptr, nullptr, 1024, 32, 32);
    rope_qk<<<dim3(16, 64), 256, 0, stream>>>(qkv_lin, cost, sint, qb, kb);
    v_mix_pack<<<dim3(16, 64), 256, 0, stream>>>(qkv_lin, gm, vres, vtb, i);
    attn_fwd<<<1024, 256, 0, stream>>>(qb, kb, vtb, gm, attn);
    gemm_nt<2><<<dim3(32, 8), 256, 0, stream>>>(attn, wo_bf, x_res, nullptr, x_res, 1024, 1024, 1024);
    rms_ff<<<ROWS, 256, 0, stream>>>(x_res, nfw + i * 1024, ffw + i * 1024, h);
    gemm_geglu128<<<704, 512, 0, stream>>>(h, win_bf, u, b_in + (size_t)i * 2 * FI, 1024, FI_PAD, 32, 22);
    gemm_nt<2><<<dim3(32, 8), 256, 0, stream>>>(u, wout_bf, x_res, b_out + i * 1024, x_res, FI_PAD, 1024, 1024);
  }
  rms_final<<<ROWS, 256, 0, stream>>>(x_res, fnw, (float*)d_out);
}

// Round 18
// 1297.550 us; speedup vs baseline: 1.0796x; 1.0017x over previous
//
#include <hip/hip_runtime.h>
#include <cstdint>
#include <cstddef>

// TransformerXL forward (B=4,N=1024,D=1024,H=16,DH=64,DEPTH=4, GEGLU FI=2730)
// R18: base = R17 (best, 1299us). Single change: gemm_geglu128 XCD decode
//      switched m-major -> n-major (m0 = wgid/nn, n0 = wgid%nn): each XCD's
//      chunk now touches 4 A-panels (1MB, L2-resident) instead of all 32
//      (8MB, thrash). Predicts FETCH 100MB -> ~50MB.

#define DEV_INLINE __device__ __forceinline__

typedef short bf16x8 __attribute__((ext_vector_type(8)));
typedef float f32x4 __attribute__((ext_vector_type(4)));

constexpr int Bsz = 4, Nseq = 1024, Dm = 1024, Hh = 16, DH = 64, NDEPTH = 4;
constexpr int FI = 2730;        // GEGLU inner dim
constexpr int FI_PAD = 2752;    // u cols padded to /64 (zero-filled)
constexpr int FI_TILE = 2816;   // per-half weight rows padded to /128
constexpr int WIDE = 2 * FI_TILE;  // 5632: 16-row groups [16a | 16g | ...]
constexpr int ROWS = Bsz * Nseq; // 4096
constexpr float EPSR = 1.1920929e-07f;

DEV_INLINE float bf2f(unsigned short u) {
  unsigned int x = ((unsigned int)u) << 16;
  float f; __builtin_memcpy(&f, &x, 4); return f;
}
DEV_INLINE unsigned short f2bf(float f) {
  unsigned int x; __builtin_memcpy(&x, &f, 4);
  unsigned int r = x + 0x7fffu + ((x >> 16) & 1u);  // RNE
  return (unsigned short)(r >> 16);
}

using gptr_t = const __attribute__((address_space(1))) void*;
using lptr_t = __attribute__((address_space(3))) void*;
DEV_INLINE void gl_lds16(const void* g, void* l) {
  __builtin_amdgcn_global_load_lds((gptr_t)g, (lptr_t)l, 16, 0, 0);
}
DEV_INLINE void fence_mem() { asm volatile("" ::: "memory"); }

// ---------------- weight fp32 -> bf16 (vectorized, with zero padding) -----------
__global__ __launch_bounds__(256)
void convf2b(const float* __restrict__ src, unsigned short* __restrict__ dst,
             int src_rows, int src_cols, int dst_cols) {
  const int r = blockIdx.y;
  const int c8 = (blockIdx.x * blockDim.x + threadIdx.x) * 8;
  if (c8 >= dst_cols) return;
  alignas(16) unsigned short o[8];
  if (r < src_rows && c8 + 8 <= src_cols) {
    const float2* p = (const float2*)&src[(size_t)r * src_cols + c8];
    const float2 v0 = p[0], v1 = p[1], v2 = p[2], v3 = p[3];
    o[0] = f2bf(v0.x); o[1] = f2bf(v0.y); o[2] = f2bf(v1.x); o[3] = f2bf(v1.y);
    o[4] = f2bf(v2.x); o[5] = f2bf(v2.y); o[6] = f2bf(v3.x); o[7] = f2bf(v3.y);
  } else {
#pragma unroll
    for (int j = 0; j < 8; ++j) {
      const int c = c8 + j;
      float v = (r < src_rows && c < src_cols) ? src[(size_t)r * src_cols + c] : 0.0f;
      o[j] = f2bf(v);
    }
  }
  *(uint4*)&dst[(size_t)r * dst_cols + c8] = *(const uint4*)o;
}

// w_in 16-row-group interleave: dst rows [32t..32t+16) = a[16t..), [+16..32) = g
__global__ __launch_bounds__(128)
void convf2b_g16(const float* __restrict__ src, unsigned short* __restrict__ dst) {
  const int p = blockIdx.y;           // 0..WIDE-1
  const int c8 = threadIdx.x * 8;     // 128 thr * 8 = 1024 cols
  const int t = p >> 5, r5 = p & 31;
  const int srow = t * 16 + (r5 & 15);
  alignas(16) unsigned short o[8];
  if (srow < FI) {
    const size_t base = ((size_t)((r5 < 16) ? 0 : 1) * FI + srow) * 1024 + c8;
    const float4 v0 = *(const float4*)&src[base];
    const float4 v1 = *(const float4*)&src[base + 4];
    o[0]=f2bf(v0.x); o[1]=f2bf(v0.y); o[2]=f2bf(v0.z); o[3]=f2bf(v0.w);
    o[4]=f2bf(v1.x); o[5]=f2bf(v1.y); o[6]=f2bf(v1.z); o[7]=f2bf(v1.w);
  } else {
#pragma unroll
    for (int j = 0; j < 8; ++j) o[j] = 0;
  }
  *(uint4*)&dst[(size_t)p * 1024 + c8] = *(const uint4*)o;
}

// ---------------- rope cos/sin tables ----------------
__global__ __launch_bounds__(256)
void rope_tables(float* __restrict__ cost, float* __restrict__ sint) {
  int idx = blockIdx.x * 256 + threadIdx.x;
  if (idx >= Nseq * 32) return;
  int n = idx >> 5, p = idx & 31;
  float freq = powf(10000.0f, -(float)(2 * p) * (1.0f / 64.0f));
  float ang = (float)n * freq;
  cost[idx] = cosf(ang);
  sint[idx] = sinf(ang);
}

// ---------------- RMSNorm variants ----------------
__global__ __launch_bounds__(256)
void rms_one(const float* __restrict__ x, const float* __restrict__ w,
             unsigned short* __restrict__ out) {
  __shared__ float sred[4];
  const int row = blockIdx.x, tid = threadIdx.x;
  const float4 v = ((const float4*)(x + (size_t)row * Dm))[tid];
  float ss = v.x * v.x + v.y * v.y + v.z * v.z + v.w * v.w;
#pragma unroll
  for (int o = 32; o >= 1; o >>= 1) ss += __shfl_xor(ss, o, 64);
  if ((tid & 63) == 0) sred[tid >> 6] = ss;
  __syncthreads();
  float rs = rsqrtf((sred[0] + sred[1] + sred[2] + sred[3]) * (1.0f / Dm) + EPSR);
  const float4 wv = ((const float4*)w)[tid];
  alignas(8) unsigned short o4[4] = { f2bf(v.x * rs * wv.x), f2bf(v.y * rs * wv.y),
                                      f2bf(v.z * rs * wv.z), f2bf(v.w * rs * wv.w) };
  *(uint2*)&out[(size_t)row * Dm + tid * 4] = *(const uint2*)o4;
}

__global__ __launch_bounds__(256)
void rms_ff(const float* __restrict__ x, const float* __restrict__ w1,
            const float* __restrict__ w2, unsigned short* __restrict__ out) {
  __shared__ float sred[4];
  const int row = blockIdx.x, tid = threadIdx.x;
  const float4 v = ((const float4*)(x + (size_t)row * Dm))[tid];
  const float4 w1v = ((const float4*)w1)[tid];
  const float4 w2v = ((const float4*)w2)[tid];
  float ss = v.x * v.x + v.y * v.y + v.z * v.z + v.w * v.w;
#pragma unroll
  for (int o = 32; o >= 1; o >>= 1) ss += __shfl_xor(ss, o, 64);
  if ((tid & 63) == 0) sred[tid >> 6] = ss;
  __syncthreads();
  float rs1 = rsqrtf((sred[0] + sred[1] + sred[2] + sred[3]) * (1.0f / Dm) + EPSR);
  float t0 = v.x * rs1 * w1v.x, t1 = v.y * rs1 * w1v.y;
  float t2 = v.z * rs1 * w1v.z, t3 = v.w * rs1 * w1v.w;
  float ss2 = t0 * t0 + t1 * t1 + t2 * t2 + t3 * t3;
#pragma unroll
  for (int o = 32; o >= 1; o >>= 1) ss2 += __shfl_xor(ss2, o, 64);
  __syncthreads();
  if ((tid & 63) == 0) sred[tid >> 6] = ss2;
  __syncthreads();
  float rs2 = rsqrtf((sred[0] + sred[1] + sred[2] + sred[3]) * (1.0f / Dm) + EPSR);
  alignas(8) unsigned short o4[4] = { f2bf(t0 * rs2 * w2v.x), f2bf(t1 * rs2 * w2v.y),
                                      f2bf(t2 * rs2 * w2v.z), f2bf(t3 * rs2 * w2v.w) };
  *(uint2*)&out[(size_t)row * Dm + tid * 4] = *(const uint2*)o4;
}

__global__ __launch_bounds__(256)
void rms_final(const float* __restrict__ x, const float* __restrict__ w,
               float* __restrict__ out) {
  __shared__ float sred[4];
  const int row = blockIdx.x, tid = threadIdx.x;
  const float4 v = ((const float4*)(x + (size_t)row * Dm))[tid];
  float ss = v.x * v.x + v.y * v.y + v.z * v.z + v.w * v.w;
#pragma unroll
  for (int o = 32; o >= 1; o >>= 1) ss += __shfl_xor(ss, o, 64);
  if ((tid & 63) == 0) sred[tid >> 6] = ss;
  __syncthreads();
  float rs = rsqrtf((sred[0] + sred[1] + sred[2] + sred[3]) * (1.0f / Dm) + EPSR);
  const float4 wv = ((const float4*)w)[tid];
  float4 o;
  o.x = v.x * rs * wv.x; o.y = v.y * rs * wv.y;
  o.z = v.z * rs * wv.z; o.w = v.w * rs * wv.w;
  ((float4*)(out + (size_t)row * Dm))[tid] = o;
}

// ---------------- 128x128 NT GEMM (R9 schedule) ----------------
// MODE: 1=sigmoid f32, 2=f32 residual(+bias)
template <int MODE>
__global__ __launch_bounds__(256)
void gemm_nt(const unsigned short* __restrict__ A,
             const unsigned short* __restrict__ Bw,
             void* __restrict__ Cout,
             const float* __restrict__ bias,
             const float* __restrict__ resid,
             int K, int ldc, int n_store) {
  __shared__ unsigned short As[2][128 * 64];
  __shared__ unsigned short Bs[2][128 * 64];
  const int tid = threadIdx.x;
  const int m0 = blockIdx.x * 128;
  const int n0 = blockIdx.y * 128;
  const int w = tid >> 6, l = tid & 63;
  const int wm = (w >> 1) * 64, wn = (w & 1) * 64;
  const int lr = l & 15, lg = l >> 4;
  const int lsub = l & 7, lrow8 = l >> 3;
  const int colsw = (lsub ^ lrow8) << 3;
  const unsigned short* gA = &A[(size_t)(m0 + w * 8 + lrow8) * K + colsw];
  const unsigned short* gB = &Bw[(size_t)(n0 + w * 8 + lrow8) * K + colsw];
  const size_t rstep = (size_t)32 * K;
  f32x4 acc[4][4] = {};

  auto stage = [&](int buf, int kt) {
    const int o = kt * 64;
#pragma unroll
    for (int i = 0; i < 4; ++i) {
      gl_lds16(gA + i * rstep + o, &As[buf][i * 2048 + w * 512]);
      gl_lds16(gB + i * rstep + o, &Bs[buf][i * 2048 + w * 512]);
    }
  };
  auto compute = [&](int buf) {
    bf16x8 af[2][4], bfr[2][4];
#pragma unroll
    for (int ks = 0; ks < 2; ++ks) {
      const int slot = (ks * 4 + lg) ^ (lr & 7);
#pragma unroll
      for (int fj = 0; fj < 4; ++fj)
        bfr[ks][fj] = *(const bf16x8*)&Bs[buf][(wn + fj * 16 + lr) * 64 + slot * 8];
#pragma unroll
      for (int fi = 0; fi < 4; ++fi)
        af[ks][fi] = *(const bf16x8*)&As[buf][(wm + fi * 16 + lr) * 64 + slot * 8];
    }
    __builtin_amdgcn_s_setprio(1);
#pragma unroll
    for (int ks = 0; ks < 2; ++ks)
#pragma unroll
      for (int fi = 0; fi < 4; ++fi)
#pragma unroll
        for (int fj = 0; fj < 4; ++fj)
          acc[fi][fj] = __builtin_amdgcn_mfma_f32_16x16x32_bf16(af[ks][fi], bfr[ks][fj], acc[fi][fj], 0, 0, 0);
    __builtin_amdgcn_s_setprio(0);
  };

  const int nk = K >> 6;
  stage(0, 0);
  asm volatile("s_waitcnt vmcnt(0)" ::: "memory");
  __builtin_amdgcn_s_barrier();
  fence_mem();
  int cur = 0;
#pragma unroll 1
  for (int kt = 0; kt < nk; ++kt) {
    const bool more = (kt + 1 < nk);
    if (more) stage(cur ^ 1, kt + 1);
    compute(cur);
    if (more) {
      asm volatile("s_waitcnt vmcnt(0)" ::: "memory");
      __builtin_amdgcn_s_barrier();
      fence_mem();
    }
    cur ^= 1;
  }

#pragma unroll
  for (int fi = 0; fi < 4; ++fi) {
    const int rowb = m0 + wm + fi * 16 + lg * 4;
#pragma unroll
    for (int fj = 0; fj < 4; ++fj) {
      const int col = n0 + wn + fj * 16 + lr;
#pragma unroll
      for (int r = 0; r < 4; ++r) {
        const float val = acc[fi][fj][r];
        const int rr = rowb + r;
        if constexpr (MODE == 1) {
          if (col < n_store)
            ((float*)Cout)[(size_t)rr * ldc + col] = 1.0f / (1.0f + __expf(-val));
        } else {  // MODE 2
          const float bv = bias ? bias[col] : 0.0f;
          ((float*)Cout)[(size_t)rr * ldc + col] =
              resid[(size_t)rr * ldc + col] + val + bv;
        }
      }
    }
  }
}

// ---------------- 256x256 NT GEMM: 512 thr, 8 waves (2Mx4N), BK=64 ----------------
// (qkv only.) 4 stage-parts per K-tile; no intra-tile barriers; tile-end
// vmcnt(0)+barrier. XCD swizzle. MODE 0 = bf16 store.
template <int MODE>
__global__ __launch_bounds__(512, 2)
void gemm_nt256(const unsigned short* __restrict__ A,
                const unsigned short* __restrict__ Bw,
                void* __restrict__ Cout,
                const float* __restrict__ bias,
                int K, int ldc, int nm, int nn) {
  __shared__ unsigned short As[2][256 * 64];
  __shared__ unsigned short Bs[2][256 * 64];
  const int tid = threadIdx.x;
  const int nwg = nm * nn;
  const int qq = nwg >> 3;
  const int xcd = blockIdx.x & 7, orig = blockIdx.x >> 3;
  const int wgid = xcd * qq + orig;
  const int m0 = (wgid % nm) * 256;
  const int n0 = (wgid / nm) * 256;
  const int w = tid >> 6, l = tid & 63;
  const int wm = (w >> 2) * 128, wn = (w & 3) * 64;
  const int lr = l & 15, lg = l >> 4;
  const int lsub = l & 7, lrow8 = l >> 3;
  const int colsw = (lsub ^ lrow8) << 3;
  const unsigned short* gA = &A[(size_t)(m0 + w * 8 + lrow8) * K + colsw];
  const unsigned short* gB = &Bw[(size_t)(n0 + w * 8 + lrow8) * K + colsw];
  const size_t rstep = (size_t)64 * K;
  f32x4 acc[8][4] = {};

  auto stage_part = [&](int buf, int kt, int part) {
    const int o = kt * 64;
    const int i0 = (part & 1) * 2;
    if (part < 2) {
      gl_lds16(gA + (size_t)i0 * rstep + o,       &As[buf][i0 * 4096 + w * 512]);
      gl_lds16(gA + (size_t)(i0 + 1) * rstep + o, &As[buf][(i0 + 1) * 4096 + w * 512]);
    } else {
      gl_lds16(gB + (size_t)i0 * rstep + o,       &Bs[buf][i0 * 4096 + w * 512]);
      gl_lds16(gB + (size_t)(i0 + 1) * rstep + o, &Bs[buf][(i0 + 1) * 4096 + w * 512]);
    }
  };

  const int nk = K >> 6;
  stage_part(0, 0, 0); stage_part(0, 0, 1);
  stage_part(0, 0, 2); stage_part(0, 0, 3);
  asm volatile("s_waitcnt vmcnt(0)" ::: "memory");
  __builtin_amdgcn_s_barrier();
  fence_mem();

#pragma unroll 1
  for (int t = 0; t < nk; ++t) {
    const int p = t & 1;
    const bool more = (t + 1 < nk);
    bf16x8 bfr[4];
#pragma unroll
    for (int q = 0; q < 4; ++q) {
      const int ks = q >> 1, half = q & 1;
      const int slot = (ks * 4 + lg) ^ (lr & 7);
      if (half == 0) {
#pragma unroll
        for (int fj = 0; fj < 4; ++fj)
          bfr[fj] = *(const bf16x8*)&Bs[p][(wn + fj * 16 + lr) * 64 + slot * 8];
      }
      bf16x8 af[4];
#pragma unroll
      for (int fi = 0; fi < 4; ++fi)
        af[fi] = *(const bf16x8*)&As[p][(wm + half * 64 + fi * 16 + lr) * 64 + slot * 8];
      if (more) stage_part(p ^ 1, t + 1, q);
      __builtin_amdgcn_s_setprio(1);
#pragma unroll
      for (int fi = 0; fi < 4; ++fi)
#pragma unroll
        for (int fj = 0; fj < 4; ++fj)
          acc[half * 4 + fi][fj] =
              __builtin_amdgcn_mfma_f32_16x16x32_bf16(af[fi], bfr[fj], acc[half * 4 + fi][fj], 0, 0, 0);
      __builtin_amdgcn_s_setprio(0);
    }
    if (more) {
      asm volatile("s_waitcnt vmcnt(0)" ::: "memory");
      __builtin_amdgcn_s_barrier();
      fence_mem();
    }
  }

#pragma unroll
  for (int fi = 0; fi < 8; ++fi) {
    const int rowb = m0 + wm + fi * 16 + lg * 4;
#pragma unroll
    for (int fj = 0; fj < 4; ++fj) {
      const int col = n0 + wn + fj * 16 + lr;
#pragma unroll
      for (int r = 0; r < 4; ++r)
        ((unsigned short*)Cout)[(size_t)(rowb + r) * ldc + col] = f2bf(acc[fi][fj][r]);
    }
  }
}

// ---------------- 128x256 NT GEMM (GEGLU): 512 thr, 8 waves (2Mx4N) ----------------
// BM=128 (wave owns 64 rows), BN=256; LDS 96KB; 704-block grid.
// n-major XCD decode: each XCD chunk spans 4 A-panels (1MB, L2-fit).
__global__ __launch_bounds__(512, 2)
void gemm_geglu128(const unsigned short* __restrict__ A,
                   const unsigned short* __restrict__ Bw,
                   unsigned short* __restrict__ Cout,
                   const float* __restrict__ bias,
                   int K, int ldc, int nm, int nn) {
  __shared__ unsigned short As[2][128 * 64];   // 16 KB each
  __shared__ unsigned short Bs[2][256 * 64];   // 32 KB each
  const int tid = threadIdx.x;
  const int nwg = nm * nn;
  const int qq = nwg >> 3;
  const int xcd = blockIdx.x & 7, orig = blockIdx.x >> 3;
  const int wgid = xcd * qq + orig;
  const int m0 = (wgid / nn) * 128;    // n-major: A-panel changes every nn blocks
  const int n0 = (wgid % nn) * 256;
  const int w = tid >> 6, l = tid & 63;
  const int wm = (w >> 2) * 64, wn = (w & 3) * 64;   // wave: 64x64
  const int lr = l & 15, lg = l >> 4;
  const int lsub = l & 7, lrow8 = l >> 3;
  const int colsw = (lsub ^ lrow8) << 3;
  const unsigned short* gA = &A[(size_t)(m0 + w * 8 + lrow8) * K + colsw];
  const unsigned short* gB = &Bw[(size_t)(n0 + w * 8 + lrow8) * K + colsw];
  const size_t rstep = (size_t)64 * K;   // 512 lanes x 8 els = 64 rows / instr
  f32x4 acc[4][4] = {};

  auto stage = [&](int buf, int kt) {
    const int o = kt * 64;
#pragma unroll
    for (int i = 0; i < 2; ++i)
      gl_lds16(gA + (size_t)i * rstep + o, &As[buf][i * 4096 + w * 512]);
#pragma unroll
    for (int i = 0; i < 4; ++i)
      gl_lds16(gB + (size_t)i * rstep + o, &Bs[buf][i * 4096 + w * 512]);
  };
  auto compute = [&](int buf) {
#pragma unroll
    for (int ks = 0; ks < 2; ++ks) {
      const int slot = (ks * 4 + lg) ^ (lr & 7);
      bf16x8 bfr[4], af[4];
#pragma unroll
      for (int fj = 0; fj < 4; ++fj)
        bfr[fj] = *(const bf16x8*)&Bs[buf][(wn + fj * 16 + lr) * 64 + slot * 8];
#pragma unroll
      for (int fi = 0; fi < 4; ++fi)
        af[fi] = *(const bf16x8*)&As[buf][(wm + fi * 16 + lr) * 64 + slot * 8];
      __builtin_amdgcn_s_setprio(1);
#pragma unroll
      for (int fi = 0; fi < 4; ++fi)
#pragma unroll
        for (int fj = 0; fj < 4; ++fj)
          acc[fi][fj] = __builtin_amdgcn_mfma_f32_16x16x32_bf16(af[fi], bfr[fj], acc[fi][fj], 0, 0, 0);
      __builtin_amdgcn_s_setprio(0);
    }
  };

  const int nk = K >> 6;
  stage(0, 0);
  asm volatile("s_waitcnt vmcnt(0)" ::: "memory");
  __builtin_amdgcn_s_barrier();
  fence_mem();
  int cur = 0;
#pragma unroll 1
  for (int kt = 0; kt < nk; ++kt) {
    const bool more = (kt + 1 < nk);
    if (more) stage(cur ^ 1, kt + 1);
    compute(cur);
    if (more) {
      asm volatile("s_waitcnt vmcnt(0)" ::: "memory");
      __builtin_amdgcn_s_barrier();
      fence_mem();
    }
    cur ^= 1;
  }

  // grouped-GEGLU epilogue: cols in 16-groups [a|g]; pair (2fjp, 2fjp+1) in-thread
#pragma unroll
  for (int fi = 0; fi < 4; ++fi) {
    const int rowb = m0 + wm + fi * 16 + lg * 4;
#pragma unroll
    for (int fjp = 0; fjp < 2; ++fjp) {
      const int ucol = ((n0 + wn) >> 1) + fjp * 16 + lr;
      if (ucol >= FI_PAD) continue;
      const bool live = (ucol < FI);
      const float ba = live ? bias[ucol] : 0.0f;
      const float bg = live ? bias[FI + ucol] : 0.0f;
#pragma unroll
      for (int r = 0; r < 4; ++r) {
        const float va = acc[fi][2 * fjp][r] + ba;
        const float vg = acc[fi][2 * fjp + 1][r] + bg;
        const float gel = 0.5f * vg * (1.0f + erff(vg * 0.70710678118654752f));
        Cout[(size_t)(rowb + r) * ldc + ucol] = f2bf(live ? va * gel : 0.0f);
      }
    }
  }
}

// ---------------- RoPE on q,k (q also * DH^-0.5) ----------------
__global__ __launch_bounds__(256)
void rope_qk(const unsigned short* __restrict__ qkv_lin,
             const float* __restrict__ cost, const float* __restrict__ sint,
             unsigned short* __restrict__ qb, unsigned short* __restrict__ kb) {
  const int nt = blockIdx.x, bh = blockIdx.y;
  const int b = bh >> 4, h = bh & 15;
  const int tid = threadIdx.x;
  const int pi = tid & 31, r0 = tid >> 5;
  const float scale = 0.125f;
#pragma unroll
  for (int j = 0; j < 8; ++j) {
    const int n = nt * 64 + r0 + j * 8;
    const int nf = b * Nseq + n;
    const float c = cost[n * 32 + pi], s = sint[n * 32 + pi];
    const unsigned short* qp = &qkv_lin[(size_t)nf * 3072 + h * 64 + pi * 2];
    float q0 = bf2f(qp[0]), q1 = bf2f(qp[1]);
    alignas(4) unsigned short oq[2];
    oq[0] = f2bf((q0 * c - q1 * s) * scale);
    oq[1] = f2bf((q1 * c + q0 * s) * scale);
    *(unsigned int*)&qb[((size_t)bh * Nseq + n) * 64 + pi * 2] = *(const unsigned int*)oq;
    const unsigned short* kp = &qkv_lin[(size_t)nf * 3072 + 1024 + h * 64 + pi * 2];
    float k0 = bf2f(kp[0]), k1 = bf2f(kp[1]);
    alignas(4) unsigned short ok[2];
    ok[0] = f2bf(k0 * c - k1 * s);
    ok[1] = f2bf(k1 * c + k0 * s);
    *(unsigned int*)&kb[((size_t)bh * Nseq + n) * 64 + pi * 2] = *(const unsigned int*)ok;
  }
}

// ---------------- v: value-residual lerp + transpose-pack ----------------
__global__ __launch_bounds__(256)
void v_mix_pack(const unsigned short* __restrict__ qkv_lin,
                const float* __restrict__ gm,
                unsigned short* __restrict__ vres,
                unsigned short* __restrict__ vtb, int layer) {
  __shared__ unsigned short T[64][72];
  const int nt = blockIdx.x, bh = blockIdx.y;
  const int b = bh >> 4, h = bh & 15;
  const int tid = threadIdx.x;
#pragma unroll
  for (int p = 0; p < 2; ++p) {
    int c = tid + p * 256;
    int nl = c >> 3, cg = (c & 7) << 3;
    int n = nt * 64 + nl, nf = b * Nseq + n;
    uint4 vv = *(const uint4*)&qkv_lin[(size_t)nf * 3072 + 2048 + h * 64 + cg];
    if (layer == 0) {
      *(uint4*)&vres[((size_t)bh * Nseq + n) * 64 + cg] = vv;
      *(uint4*)&T[nl][cg] = vv;
    } else {
      alignas(16) unsigned short ve[8]; *(uint4*)ve = vv;
      uint4 rv = *(const uint4*)&vres[((size_t)bh * Nseq + n) * 64 + cg];
      alignas(16) unsigned short re[8]; *(uint4*)re = rv;
      const float mix = gm[(size_t)nf * 32 + 16 + h];
      alignas(16) unsigned short oe[8];
#pragma unroll
      for (int j = 0; j < 8; ++j) {
        float v = bf2f(ve[j]), rr = bf2f(re[j]);
        oe[j] = f2bf(v + mix * (rr - v));
      }
      *(uint4*)&T[nl][cg] = *(const uint4*)oe;
    }
  }
  __syncthreads();
#pragma unroll
  for (int p = 0; p < 2; ++p) {
    int c = tid + p * 256;
    int d = c >> 3, ng = (c & 7) << 3;
    alignas(16) unsigned short oe[8];
#pragma unroll
    for (int j = 0; j < 8; ++j) oe[j] = T[ng + j][d];
    *(uint4*)&vtb[(size_t)bh * 65536 + (size_t)d * Nseq + nt * 64 + ng] = *(const uint4*)oe;
  }
}

// ---------------- causal flash attention + gate + head-merge ----------------
__global__ __launch_bounds__(256)
void attn_fwd(const unsigned short* __restrict__ qb,
              const unsigned short* __restrict__ kb,
              const unsigned short* __restrict__ vtb,
              const float* __restrict__ gm,
              unsigned short* __restrict__ attn_out) {
  __shared__ unsigned short Ks[2][64 * 64];   // [key][dh], swizzled
  __shared__ unsigned short Vs[2][64 * 64];   // V^T: [dh][key], swizzled
  __shared__ unsigned short Ps[4][16][72];
  const int bid = blockIdx.x;
  const int x = bid & 7, rest = bid >> 3;
  const int bh = x * 8 + (rest & 7);
  const int qt = 15 - (rest >> 3);
  const int b = bh >> 4, h = bh & 15;
  const int tid = threadIdx.x;
  const int w = tid >> 6, l = tid & 63;
  const int lr = l & 15, lg = l >> 4;
  const int q0 = qt * 64 + w * 16;
  const size_t head = (size_t)bh * Nseq * DH;
  const int lrow8 = l >> 3;
  const int colsw = ((l & 7) ^ lrow8) << 3;

  auto stageKV = [&](int buf, int kt) {
    const int kv0 = kt * 64;
#pragma unroll
    for (int i = 0; i < 2; ++i) {
      const int rb = w * 16 + i * 8;
      gl_lds16(&kb[head + (size_t)(kv0 + rb + lrow8) * DH + colsw],
               &Ks[buf][rb * 64]);
      gl_lds16(&vtb[head + (size_t)(rb + lrow8) * Nseq + kv0 + colsw],
               &Vs[buf][rb * 64]);
    }
  };

  bf16x8 aq[2];
  aq[0] = *(const bf16x8*)&qb[head + (size_t)(q0 + lr) * DH + lg * 8];
  aq[1] = *(const bf16x8*)&qb[head + (size_t)(q0 + lr) * DH + 32 + lg * 8];

  float mrow[4] = {-1e30f, -1e30f, -1e30f, -1e30f};
  float lsum[4] = {0.f, 0.f, 0.f, 0.f};
  f32x4 acco[4] = {};

  stageKV(0, 0);
  asm volatile("s_waitcnt vmcnt(0)" ::: "memory");
  __builtin_amdgcn_s_barrier();
  fence_mem();

#pragma unroll 1
  for (int kt = 0; kt <= qt; ++kt) {
    const int p = kt & 1;
    const int kv0 = kt * 64;
    const bool more = (kt < qt);
    if (more) stageKV(p ^ 1, kt + 1);      // async prefetch next K/V tile
    f32x4 s[4];
#pragma unroll
    for (int t = 0; t < 4; ++t) {
      const int krow = t * 16 + lr;
      bf16x8 bk0 = *(const bf16x8*)&Ks[p][krow * 64 + ((0 + lg) ^ (lr & 7)) * 8];
      bf16x8 bk1 = *(const bf16x8*)&Ks[p][krow * 64 + ((4 + lg) ^ (lr & 7)) * 8];
      f32x4 z = {};
      z = __builtin_amdgcn_mfma_f32_16x16x32_bf16(aq[0], bk0, z, 0, 0, 0);
      z = __builtin_amdgcn_mfma_f32_16x16x32_bf16(aq[1], bk1, z, 0, 0, 0);
      s[t] = z;
    }
    const bool diag = (kt == qt);
    float mx4[4];
    bool need = false;
#pragma unroll
    for (int r = 0; r < 4; ++r) {
      const int qr = q0 + lg * 4 + r;
      float mx = -1e30f;
#pragma unroll
      for (int t = 0; t < 4; ++t) {
        float sv = s[t][r];
        if (diag && (kv0 + t * 16 + lr > qr)) sv = -1e30f;
        s[t][r] = sv;
        mx = fmaxf(mx, sv);
      }
      mx = fmaxf(mx, __shfl_xor(mx, 1, 64));
      mx = fmaxf(mx, __shfl_xor(mx, 2, 64));
      mx = fmaxf(mx, __shfl_xor(mx, 4, 64));
      mx = fmaxf(mx, __shfl_xor(mx, 8, 64));
      mx4[r] = mx;
      need = need || (mx > mrow[r] + 8.0f);
    }
    if (__any(need)) {    // defer-max
#pragma unroll
      for (int r = 0; r < 4; ++r) {
        const float mn = fmaxf(mrow[r], mx4[r]);
        const float alpha = __expf(mrow[r] - mn);
        mrow[r] = mn;
        lsum[r] *= alpha;
#pragma unroll
        for (int dt = 0; dt < 4; ++dt) acco[dt][r] *= alpha;
      }
    }
#pragma unroll
    for (int r = 0; r < 4; ++r) {
      float rs = 0.f;
#pragma unroll
      for (int t = 0; t < 4; ++t) {
        float pv = __expf(s[t][r] - mrow[r]);   // bounded by e^8
        s[t][r] = pv;
        rs += pv;
      }
      rs += __shfl_xor(rs, 1, 64);
      rs += __shfl_xor(rs, 2, 64);
      rs += __shfl_xor(rs, 4, 64);
      rs += __shfl_xor(rs, 8, 64);
      lsum[r] += rs;
    }
#pragma unroll
    for (int t = 0; t < 4; ++t)
#pragma unroll
      for (int r = 0; r < 4; ++r)
        Ps[w][lg * 4 + r][t * 16 + lr] = f2bf(s[t][r]);
#pragma unroll
    for (int ks = 0; ks < 2; ++ks) {
      bf16x8 ap = *(const bf16x8*)&Ps[w][lr][ks * 32 + lg * 8];
#pragma unroll
      for (int dt = 0; dt < 4; ++dt) {
        const int vrow = dt * 16 + lr;
        bf16x8 bv = *(const bf16x8*)&Vs[p][vrow * 64 + ((ks * 4 + lg) ^ (lr & 7)) * 8];
        acco[dt] = __builtin_amdgcn_mfma_f32_16x16x32_bf16(ap, bv, acco[dt], 0, 0, 0);
      }
    }
    if (more) {
      asm volatile("s_waitcnt vmcnt(0)" ::: "memory");  // next tile landed
      __builtin_amdgcn_s_barrier();                     // all waves done with buf p
      fence_mem();
    }
  }

#pragma unroll
  for (int r = 0; r < 4; ++r) {
    const int qr = q0 + lg * 4 + r;
    const int nf = b * Nseq + qr;
    const float gate = gm[(size_t)nf * 32 + h];
    const float inv = 1.0f / lsum[r];
#pragma unroll
    for (int dt = 0; dt < 4; ++dt)
      attn_out[(size_t)nf * Dm + h * DH + dt * 16 + lr] = f2bf(acco[dt][r] * inv * gate);
  }
}

// ---------------- host launch ----------------
extern "C" void kernel_launch(void* const* d_in, const int* in_sizes, int n_in,
                              void* d_out, int out_size, void* d_ws, size_t ws_size,
                              hipStream_t stream) {
  const float* x_in  = (const float*)d_in[0];
  const float* naw   = (const float*)d_in[1];
  const float* wq    = (const float*)d_in[2];
  const float* wkv   = (const float*)d_in[3];
  const float* wo    = (const float*)d_in[4];
  const float* wg    = (const float*)d_in[5];
  const float* wmix  = (const float*)d_in[6];
  const float* nfw   = (const float*)d_in[7];
  const float* ffw   = (const float*)d_in[8];
  const float* w_in  = (const float*)d_in[9];
  const float* b_in  = (const float*)d_in[10];
  const float* w_out = (const float*)d_in[11];
  const float* b_out = (const float*)d_in[12];
  const float* fnw   = (const float*)d_in[13];

  uint8_t* ws = (uint8_t*)d_ws;
  size_t off = 0;
  auto alloc = [&](size_t bytes) -> void* {
    void* p = ws + off;
    off += (bytes + 255) & ~(size_t)255;
    return p;
  };
  float*          x_res    = (float*)alloc((size_t)ROWS * Dm * 4);
  unsigned short* h        = (unsigned short*)alloc((size_t)ROWS * Dm * 2);
  unsigned short* qkv_lin  = (unsigned short*)alloc((size_t)ROWS * 3072 * 2);
  float*          gm       = (float*)alloc((size_t)ROWS * 32 * 4);
  unsigned short* qb       = (unsigned short*)alloc((size_t)64 * Nseq * DH * 2);
  unsigned short* kb       = (unsigned short*)alloc((size_t)64 * Nseq * DH * 2);
  unsigned short* vtb      = (unsigned short*)alloc((size_t)64 * Nseq * DH * 2);
  unsigned short* vres     = (unsigned short*)alloc((size_t)64 * Nseq * DH * 2);
  unsigned short* attn     = (unsigned short*)alloc((size_t)ROWS * Dm * 2);
  float*          cost     = (float*)alloc((size_t)Nseq * 32 * 4);
  float*          sint     = (float*)alloc((size_t)Nseq * 32 * 4);
  unsigned short* wqkv_bf  = (unsigned short*)alloc((size_t)3072 * 1024 * 2);
  unsigned short* wo_bf    = (unsigned short*)alloc((size_t)1024 * 1024 * 2);
  unsigned short* wgm_bf   = (unsigned short*)alloc((size_t)128 * 1024 * 2);
  unsigned short* win_bf   = (unsigned short*)alloc((size_t)WIDE * 1024 * 2);  // 16-row groups
  unsigned short* wout_bf  = (unsigned short*)alloc((size_t)1024 * FI_PAD * 2);
  unsigned short* u = qkv_lin;  // alias: qkv scratch dead before FF uses u

  hipMemcpyAsync(x_res, x_in, (size_t)ROWS * Dm * 4, hipMemcpyDeviceToDevice, stream);
  rope_tables<<<128, 256, 0, stream>>>(cost, sint);

  for (int i = 0; i < NDEPTH; ++i) {
    convf2b<<<dim3(1, 1024), 128, 0, stream>>>(wq + (size_t)i * 1024 * 1024, wqkv_bf, 1024, 1024, 1024);
    convf2b<<<dim3(1, 2048), 128, 0, stream>>>(wkv + (size_t)i * 2048 * 1024, wqkv_bf + (size_t)1024 * 1024, 2048, 1024, 1024);
    convf2b<<<dim3(1, 1024), 128, 0, stream>>>(wo + (size_t)i * 1024 * 1024, wo_bf, 1024, 1024, 1024);
    convf2b<<<dim3(1, 16), 128, 0, stream>>>(wg + (size_t)i * 16 * 1024, wgm_bf, 16, 1024, 1024);
    convf2b<<<dim3(1, 16), 128, 0, stream>>>(wmix + (size_t)i * 16 * 1024, wgm_bf + 16 * 1024, 16, 1024, 1024);
    convf2b<<<dim3(1, 96), 128, 0, stream>>>(wg, wgm_bf + 32 * 1024, 0, 1024, 1024);  // zero rows 32..127
    convf2b_g16<<<dim3(1, WIDE), 128, 0, stream>>>(w_in + (size_t)i * 2 * FI * 1024, win_bf);
    convf2b<<<dim3(2, 1024), 256, 0, stream>>>(w_out + (size_t)i * 1024 * FI, wout_bf, 1024, FI, FI_PAD);

    rms_one<<<ROWS, 256, 0, stream>>>(x_res, naw + i * 1024, h);
    gemm_nt256<0><<<192, 512, 0, stream>>>(h, wqkv_bf, qkv_lin, nullptr, 1024, 3072, 16, 12);
    gemm_nt<1><<<dim3(32, 1), 256, 0, stream>>>(h, wgm_bf, gm, nullptr, nullptr, 1024, 32, 32);
    rope_qk<<<dim3(16, 64), 256, 0, stream>>>(qkv_lin, cost, sint, qb, kb);
    v_mix_pack<<<dim3(16, 64), 256, 0, stream>>>(qkv_lin, gm, vres, vtb, i);
    attn_fwd<<<1024, 256, 0, stream>>>(qb, kb, vtb, gm, attn);
    gemm_nt<2><<<dim3(32, 8), 256, 0, stream>>>(attn, wo_bf, x_res, nullptr, x_res, 1024, 1024, 1024);
    rms_ff<<<ROWS, 256, 0, stream>>>(x_res, nfw + i * 1024, ffw + i * 1024, h);
    gemm_geglu128<<<704, 512, 0, stream>>>(h, win_bf, u, b_in + (size_t)i * 2 * FI, 1024, FI_PAD, 32, 22);
    gemm_nt<2><<<dim3(32, 8), 256, 0, stream>>>(u, wout_bf, x_res, b_out + i * 1024, x_res, FI_PAD, 1024, 1024);
  }
  rms_final<<<ROWS, 256, 0, stream>>>(x_res, fnw, (float*)d_out);
}

// Round 19
// 1250.398 us; speedup vs baseline: 1.1203x; 1.0377x over previous
//
#include <hip/hip_runtime.h>
#include <cstdint>
#include <cstddef>

// TransformerXL forward (B=4,N=1024,D=1024,H=16,DH=64,DEPTH=4, GEGLU FI=2730)
// R19: base = R18 (best, 1297us). Host-side restructure only:
//  (1) all weight conversions batched across layers (grid.z=4) -> 8 dispatches
//      total instead of 32 (weight buffers x4 layers, +~77MB ws);
//  (2) rope_qk + v_mix_pack fused into one kernel.
//  71 -> 47 dispatches; all hot inner loops byte-identical to R18.

#define DEV_INLINE __device__ __forceinline__

typedef short bf16x8 __attribute__((ext_vector_type(8)));
typedef float f32x4 __attribute__((ext_vector_type(4)));

constexpr int Bsz = 4, Nseq = 1024, Dm = 1024, Hh = 16, DH = 64, NDEPTH = 4;
constexpr int FI = 2730;        // GEGLU inner dim
constexpr int FI_PAD = 2752;    // u cols padded to /64 (zero-filled)
constexpr int FI_TILE = 2816;   // per-half weight rows padded to /128
constexpr int WIDE = 2 * FI_TILE;  // 5632: 16-row groups [16a | 16g | ...]
constexpr int ROWS = Bsz * Nseq; // 4096
constexpr float EPSR = 1.1920929e-07f;

DEV_INLINE float bf2f(unsigned short u) {
  unsigned int x = ((unsigned int)u) << 16;
  float f; __builtin_memcpy(&f, &x, 4); return f;
}
DEV_INLINE unsigned short f2bf(float f) {
  unsigned int x; __builtin_memcpy(&x, &f, 4);
  unsigned int r = x + 0x7fffu + ((x >> 16) & 1u);  // RNE
  return (unsigned short)(r >> 16);
}

using gptr_t = const __attribute__((address_space(1))) void*;
using lptr_t = __attribute__((address_space(3))) void*;
DEV_INLINE void gl_lds16(const void* g, void* l) {
  __builtin_amdgcn_global_load_lds((gptr_t)g, (lptr_t)l, 16, 0, 0);
}
DEV_INLINE void fence_mem() { asm volatile("" ::: "memory"); }

// ------------- weight fp32 -> bf16 (vectorized, padded, layer-batched) ----------
__global__ __launch_bounds__(256)
void convf2b(const float* __restrict__ src, unsigned short* __restrict__ dst,
             int src_rows, int src_cols, int dst_cols,
             size_t sstride, size_t dstride) {
  const int L = blockIdx.z;
  src += (size_t)L * sstride;
  dst += (size_t)L * dstride;
  const int r = blockIdx.y;
  const int c8 = (blockIdx.x * blockDim.x + threadIdx.x) * 8;
  if (c8 >= dst_cols) return;
  alignas(16) unsigned short o[8];
  if (r < src_rows && c8 + 8 <= src_cols) {
    const float2* p = (const float2*)&src[(size_t)r * src_cols + c8];
    const float2 v0 = p[0], v1 = p[1], v2 = p[2], v3 = p[3];
    o[0] = f2bf(v0.x); o[1] = f2bf(v0.y); o[2] = f2bf(v1.x); o[3] = f2bf(v1.y);
    o[4] = f2bf(v2.x); o[5] = f2bf(v2.y); o[6] = f2bf(v3.x); o[7] = f2bf(v3.y);
  } else {
#pragma unroll
    for (int j = 0; j < 8; ++j) {
      const int c = c8 + j;
      float v = (r < src_rows && c < src_cols) ? src[(size_t)r * src_cols + c] : 0.0f;
      o[j] = f2bf(v);
    }
  }
  *(uint4*)&dst[(size_t)r * dst_cols + c8] = *(const uint4*)o;
}

// w_in 16-row-group interleave (layer-batched): rows [32t..32t+16)=a, [+16..32)=g
__global__ __launch_bounds__(128)
void convf2b_g16(const float* __restrict__ src, unsigned short* __restrict__ dst) {
  const int L = blockIdx.z;
  src += (size_t)L * 2 * FI * 1024;
  dst += (size_t)L * WIDE * 1024;
  const int p = blockIdx.y;           // 0..WIDE-1
  const int c8 = threadIdx.x * 8;     // 128 thr * 8 = 1024 cols
  const int t = p >> 5, r5 = p & 31;
  const int srow = t * 16 + (r5 & 15);
  alignas(16) unsigned short o[8];
  if (srow < FI) {
    const size_t base = ((size_t)((r5 < 16) ? 0 : 1) * FI + srow) * 1024 + c8;
    const float4 v0 = *(const float4*)&src[base];
    const float4 v1 = *(const float4*)&src[base + 4];
    o[0]=f2bf(v0.x); o[1]=f2bf(v0.y); o[2]=f2bf(v0.z); o[3]=f2bf(v0.w);
    o[4]=f2bf(v1.x); o[5]=f2bf(v1.y); o[6]=f2bf(v1.z); o[7]=f2bf(v1.w);
  } else {
#pragma unroll
    for (int j = 0; j < 8; ++j) o[j] = 0;
  }
  *(uint4*)&dst[(size_t)p * 1024 + c8] = *(const uint4*)o;
}

// ---------------- rope cos/sin tables ----------------
__global__ __launch_bounds__(256)
void rope_tables(float* __restrict__ cost, float* __restrict__ sint) {
  int idx = blockIdx.x * 256 + threadIdx.x;
  if (idx >= Nseq * 32) return;
  int n = idx >> 5, p = idx & 31;
  float freq = powf(10000.0f, -(float)(2 * p) * (1.0f / 64.0f));
  float ang = (float)n * freq;
  cost[idx] = cosf(ang);
  sint[idx] = sinf(ang);
}

// ---------------- RMSNorm variants ----------------
__global__ __launch_bounds__(256)
void rms_one(const float* __restrict__ x, const float* __restrict__ w,
             unsigned short* __restrict__ out) {
  __shared__ float sred[4];
  const int row = blockIdx.x, tid = threadIdx.x;
  const float4 v = ((const float4*)(x + (size_t)row * Dm))[tid];
  float ss = v.x * v.x + v.y * v.y + v.z * v.z + v.w * v.w;
#pragma unroll
  for (int o = 32; o >= 1; o >>= 1) ss += __shfl_xor(ss, o, 64);
  if ((tid & 63) == 0) sred[tid >> 6] = ss;
  __syncthreads();
  float rs = rsqrtf((sred[0] + sred[1] + sred[2] + sred[3]) * (1.0f / Dm) + EPSR);
  const float4 wv = ((const float4*)w)[tid];
  alignas(8) unsigned short o4[4] = { f2bf(v.x * rs * wv.x), f2bf(v.y * rs * wv.y),
                                      f2bf(v.z * rs * wv.z), f2bf(v.w * rs * wv.w) };
  *(uint2*)&out[(size_t)row * Dm + tid * 4] = *(const uint2*)o4;
}

__global__ __launch_bounds__(256)
void rms_ff(const float* __restrict__ x, const float* __restrict__ w1,
            const float* __restrict__ w2, unsigned short* __restrict__ out) {
  __shared__ float sred[4];
  const int row = blockIdx.x, tid = threadIdx.x;
  const float4 v = ((const float4*)(x + (size_t)row * Dm))[tid];
  const float4 w1v = ((const float4*)w1)[tid];
  const float4 w2v = ((const float4*)w2)[tid];
  float ss = v.x * v.x + v.y * v.y + v.z * v.z + v.w * v.w;
#pragma unroll
  for (int o = 32; o >= 1; o >>= 1) ss += __shfl_xor(ss, o, 64);
  if ((tid & 63) == 0) sred[tid >> 6] = ss;
  __syncthreads();
  float rs1 = rsqrtf((sred[0] + sred[1] + sred[2] + sred[3]) * (1.0f / Dm) + EPSR);
  float t0 = v.x * rs1 * w1v.x, t1 = v.y * rs1 * w1v.y;
  float t2 = v.z * rs1 * w1v.z, t3 = v.w * rs1 * w1v.w;
  float ss2 = t0 * t0 + t1 * t1 + t2 * t2 + t3 * t3;
#pragma unroll
  for (int o = 32; o >= 1; o >>= 1) ss2 += __shfl_xor(ss2, o, 64);
  __syncthreads();
  if ((tid & 63) == 0) sred[tid >> 6] = ss2;
  __syncthreads();
  float rs2 = rsqrtf((sred[0] + sred[1] + sred[2] + sred[3]) * (1.0f / Dm) + EPSR);
  alignas(8) unsigned short o4[4] = { f2bf(t0 * rs2 * w2v.x), f2bf(t1 * rs2 * w2v.y),
                                      f2bf(t2 * rs2 * w2v.z), f2bf(t3 * rs2 * w2v.w) };
  *(uint2*)&out[(size_t)row * Dm + tid * 4] = *(const uint2*)o4;
}

__global__ __launch_bounds__(256)
void rms_final(const float* __restrict__ x, const float* __restrict__ w,
               float* __restrict__ out) {
  __shared__ float sred[4];
  const int row = blockIdx.x, tid = threadIdx.x;
  const float4 v = ((const float4*)(x + (size_t)row * Dm))[tid];
  float ss = v.x * v.x + v.y * v.y + v.z * v.z + v.w * v.w;
#pragma unroll
  for (int o = 32; o >= 1; o >>= 1) ss += __shfl_xor(ss, o, 64);
  if ((tid & 63) == 0) sred[tid >> 6] = ss;
  __syncthreads();
  float rs = rsqrtf((sred[0] + sred[1] + sred[2] + sred[3]) * (1.0f / Dm) + EPSR);
  const float4 wv = ((const float4*)w)[tid];
  float4 o;
  o.x = v.x * rs * wv.x; o.y = v.y * rs * wv.y;
  o.z = v.z * rs * wv.z; o.w = v.w * rs * wv.w;
  ((float4*)(out + (size_t)row * Dm))[tid] = o;
}

// ---------------- 128x128 NT GEMM (R9 schedule) ----------------
// MODE: 1=sigmoid f32, 2=f32 residual(+bias)
template <int MODE>
__global__ __launch_bounds__(256)
void gemm_nt(const unsigned short* __restrict__ A,
             const unsigned short* __restrict__ Bw,
             void* __restrict__ Cout,
             const float* __restrict__ bias,
             const float* __restrict__ resid,
             int K, int ldc, int n_store) {
  __shared__ unsigned short As[2][128 * 64];
  __shared__ unsigned short Bs[2][128 * 64];
  const int tid = threadIdx.x;
  const int m0 = blockIdx.x * 128;
  const int n0 = blockIdx.y * 128;
  const int w = tid >> 6, l = tid & 63;
  const int wm = (w >> 1) * 64, wn = (w & 1) * 64;
  const int lr = l & 15, lg = l >> 4;
  const int lsub = l & 7, lrow8 = l >> 3;
  const int colsw = (lsub ^ lrow8) << 3;
  const unsigned short* gA = &A[(size_t)(m0 + w * 8 + lrow8) * K + colsw];
  const unsigned short* gB = &Bw[(size_t)(n0 + w * 8 + lrow8) * K + colsw];
  const size_t rstep = (size_t)32 * K;
  f32x4 acc[4][4] = {};

  auto stage = [&](int buf, int kt) {
    const int o = kt * 64;
#pragma unroll
    for (int i = 0; i < 4; ++i) {
      gl_lds16(gA + i * rstep + o, &As[buf][i * 2048 + w * 512]);
      gl_lds16(gB + i * rstep + o, &Bs[buf][i * 2048 + w * 512]);
    }
  };
  auto compute = [&](int buf) {
    bf16x8 af[2][4], bfr[2][4];
#pragma unroll
    for (int ks = 0; ks < 2; ++ks) {
      const int slot = (ks * 4 + lg) ^ (lr & 7);
#pragma unroll
      for (int fj = 0; fj < 4; ++fj)
        bfr[ks][fj] = *(const bf16x8*)&Bs[buf][(wn + fj * 16 + lr) * 64 + slot * 8];
#pragma unroll
      for (int fi = 0; fi < 4; ++fi)
        af[ks][fi] = *(const bf16x8*)&As[buf][(wm + fi * 16 + lr) * 64 + slot * 8];
    }
    __builtin_amdgcn_s_setprio(1);
#pragma unroll
    for (int ks = 0; ks < 2; ++ks)
#pragma unroll
      for (int fi = 0; fi < 4; ++fi)
#pragma unroll
        for (int fj = 0; fj < 4; ++fj)
          acc[fi][fj] = __builtin_amdgcn_mfma_f32_16x16x32_bf16(af[ks][fi], bfr[ks][fj], acc[fi][fj], 0, 0, 0);
    __builtin_amdgcn_s_setprio(0);
  };

  const int nk = K >> 6;
  stage(0, 0);
  asm volatile("s_waitcnt vmcnt(0)" ::: "memory");
  __builtin_amdgcn_s_barrier();
  fence_mem();
  int cur = 0;
#pragma unroll 1
  for (int kt = 0; kt < nk; ++kt) {
    const bool more = (kt + 1 < nk);
    if (more) stage(cur ^ 1, kt + 1);
    compute(cur);
    if (more) {
      asm volatile("s_waitcnt vmcnt(0)" ::: "memory");
      __builtin_amdgcn_s_barrier();
      fence_mem();
    }
    cur ^= 1;
  }

#pragma unroll
  for (int fi = 0; fi < 4; ++fi) {
    const int rowb = m0 + wm + fi * 16 + lg * 4;
#pragma unroll
    for (int fj = 0; fj < 4; ++fj) {
      const int col = n0 + wn + fj * 16 + lr;
#pragma unroll
      for (int r = 0; r < 4; ++r) {
        const float val = acc[fi][fj][r];
        const int rr = rowb + r;
        if constexpr (MODE == 1) {
          if (col < n_store)
            ((float*)Cout)[(size_t)rr * ldc + col] = 1.0f / (1.0f + __expf(-val));
        } else {  // MODE 2
          const float bv = bias ? bias[col] : 0.0f;
          ((float*)Cout)[(size_t)rr * ldc + col] =
              resid[(size_t)rr * ldc + col] + val + bv;
        }
      }
    }
  }
}

// ---------------- 256x256 NT GEMM: 512 thr, 8 waves (2Mx4N), BK=64 ----------------
// (qkv only.) 4 stage-parts per K-tile; no intra-tile barriers; tile-end
// vmcnt(0)+barrier. XCD swizzle. MODE 0 = bf16 store.
template <int MODE>
__global__ __launch_bounds__(512, 2)
void gemm_nt256(const unsigned short* __restrict__ A,
                const unsigned short* __restrict__ Bw,
                void* __restrict__ Cout,
                const float* __restrict__ bias,
                int K, int ldc, int nm, int nn) {
  __shared__ unsigned short As[2][256 * 64];
  __shared__ unsigned short Bs[2][256 * 64];
  const int tid = threadIdx.x;
  const int nwg = nm * nn;
  const int qq = nwg >> 3;
  const int xcd = blockIdx.x & 7, orig = blockIdx.x >> 3;
  const int wgid = xcd * qq + orig;
  const int m0 = (wgid % nm) * 256;
  const int n0 = (wgid / nm) * 256;
  const int w = tid >> 6, l = tid & 63;
  const int wm = (w >> 2) * 128, wn = (w & 3) * 64;
  const int lr = l & 15, lg = l >> 4;
  const int lsub = l & 7, lrow8 = l >> 3;
  const int colsw = (lsub ^ lrow8) << 3;
  const unsigned short* gA = &A[(size_t)(m0 + w * 8 + lrow8) * K + colsw];
  const unsigned short* gB = &Bw[(size_t)(n0 + w * 8 + lrow8) * K + colsw];
  const size_t rstep = (size_t)64 * K;
  f32x4 acc[8][4] = {};

  auto stage_part = [&](int buf, int kt, int part) {
    const int o = kt * 64;
    const int i0 = (part & 1) * 2;
    if (part < 2) {
      gl_lds16(gA + (size_t)i0 * rstep + o,       &As[buf][i0 * 4096 + w * 512]);
      gl_lds16(gA + (size_t)(i0 + 1) * rstep + o, &As[buf][(i0 + 1) * 4096 + w * 512]);
    } else {
      gl_lds16(gB + (size_t)i0 * rstep + o,       &Bs[buf][i0 * 4096 + w * 512]);
      gl_lds16(gB + (size_t)(i0 + 1) * rstep + o, &Bs[buf][(i0 + 1) * 4096 + w * 512]);
    }
  };

  const int nk = K >> 6;
  stage_part(0, 0, 0); stage_part(0, 0, 1);
  stage_part(0, 0, 2); stage_part(0, 0, 3);
  asm volatile("s_waitcnt vmcnt(0)" ::: "memory");
  __builtin_amdgcn_s_barrier();
  fence_mem();

#pragma unroll 1
  for (int t = 0; t < nk; ++t) {
    const int p = t & 1;
    const bool more = (t + 1 < nk);
    bf16x8 bfr[4];
#pragma unroll
    for (int q = 0; q < 4; ++q) {
      const int ks = q >> 1, half = q & 1;
      const int slot = (ks * 4 + lg) ^ (lr & 7);
      if (half == 0) {
#pragma unroll
        for (int fj = 0; fj < 4; ++fj)
          bfr[fj] = *(const bf16x8*)&Bs[p][(wn + fj * 16 + lr) * 64 + slot * 8];
      }
      bf16x8 af[4];
#pragma unroll
      for (int fi = 0; fi < 4; ++fi)
        af[fi] = *(const bf16x8*)&As[p][(wm + half * 64 + fi * 16 + lr) * 64 + slot * 8];
      if (more) stage_part(p ^ 1, t + 1, q);
      __builtin_amdgcn_s_setprio(1);
#pragma unroll
      for (int fi = 0; fi < 4; ++fi)
#pragma unroll
        for (int fj = 0; fj < 4; ++fj)
          acc[half * 4 + fi][fj] =
              __builtin_amdgcn_mfma_f32_16x16x32_bf16(af[fi], bfr[fj], acc[half * 4 + fi][fj], 0, 0, 0);
      __builtin_amdgcn_s_setprio(0);
    }
    if (more) {
      asm volatile("s_waitcnt vmcnt(0)" ::: "memory");
      __builtin_amdgcn_s_barrier();
      fence_mem();
    }
  }

#pragma unroll
  for (int fi = 0; fi < 8; ++fi) {
    const int rowb = m0 + wm + fi * 16 + lg * 4;
#pragma unroll
    for (int fj = 0; fj < 4; ++fj) {
      const int col = n0 + wn + fj * 16 + lr;
#pragma unroll
      for (int r = 0; r < 4; ++r)
        ((unsigned short*)Cout)[(size_t)(rowb + r) * ldc + col] = f2bf(acc[fi][fj][r]);
    }
  }
}

// ---------------- 128x256 NT GEMM (GEGLU): 512 thr, 8 waves ----------------
// BM=128 (wave owns 64 rows), BN=256; LDS 96KB; 704-block grid; n-major decode.
__global__ __launch_bounds__(512, 2)
void gemm_geglu128(const unsigned short* __restrict__ A,
                   const unsigned short* __restrict__ Bw,
                   unsigned short* __restrict__ Cout,
                   const float* __restrict__ bias,
                   int K, int ldc, int nm, int nn) {
  __shared__ unsigned short As[2][128 * 64];   // 16 KB each
  __shared__ unsigned short Bs[2][256 * 64];   // 32 KB each
  const int tid = threadIdx.x;
  const int nwg = nm * nn;
  const int qq = nwg >> 3;
  const int xcd = blockIdx.x & 7, orig = blockIdx.x >> 3;
  const int wgid = xcd * qq + orig;
  const int m0 = (wgid / nn) * 128;    // n-major
  const int n0 = (wgid % nn) * 256;
  const int w = tid >> 6, l = tid & 63;
  const int wm = (w >> 2) * 64, wn = (w & 3) * 64;   // wave: 64x64
  const int lr = l & 15, lg = l >> 4;
  const int lsub = l & 7, lrow8 = l >> 3;
  const int colsw = (lsub ^ lrow8) << 3;
  const unsigned short* gA = &A[(size_t)(m0 + w * 8 + lrow8) * K + colsw];
  const unsigned short* gB = &Bw[(size_t)(n0 + w * 8 + lrow8) * K + colsw];
  const size_t rstep = (size_t)64 * K;
  f32x4 acc[4][4] = {};

  auto stage = [&](int buf, int kt) {
    const int o = kt * 64;
#pragma unroll
    for (int i = 0; i < 2; ++i)
      gl_lds16(gA + (size_t)i * rstep + o, &As[buf][i * 4096 + w * 512]);
#pragma unroll
    for (int i = 0; i < 4; ++i)
      gl_lds16(gB + (size_t)i * rstep + o, &Bs[buf][i * 4096 + w * 512]);
  };
  auto compute = [&](int buf) {
#pragma unroll
    for (int ks = 0; ks < 2; ++ks) {
      const int slot = (ks * 4 + lg) ^ (lr & 7);
      bf16x8 bfr[4], af[4];
#pragma unroll
      for (int fj = 0; fj < 4; ++fj)
        bfr[fj] = *(const bf16x8*)&Bs[buf][(wn + fj * 16 + lr) * 64 + slot * 8];
#pragma unroll
      for (int fi = 0; fi < 4; ++fi)
        af[fi] = *(const bf16x8*)&As[buf][(wm + fi * 16 + lr) * 64 + slot * 8];
      __builtin_amdgcn_s_setprio(1);
#pragma unroll
      for (int fi = 0; fi < 4; ++fi)
#pragma unroll
        for (int fj = 0; fj < 4; ++fj)
          acc[fi][fj] = __builtin_amdgcn_mfma_f32_16x16x32_bf16(af[fi], bfr[fj], acc[fi][fj], 0, 0, 0);
      __builtin_amdgcn_s_setprio(0);
    }
  };

  const int nk = K >> 6;
  stage(0, 0);
  asm volatile("s_waitcnt vmcnt(0)" ::: "memory");
  __builtin_amdgcn_s_barrier();
  fence_mem();
  int cur = 0;
#pragma unroll 1
  for (int kt = 0; kt < nk; ++kt) {
    const bool more = (kt + 1 < nk);
    if (more) stage(cur ^ 1, kt + 1);
    compute(cur);
    if (more) {
      asm volatile("s_waitcnt vmcnt(0)" ::: "memory");
      __builtin_amdgcn_s_barrier();
      fence_mem();
    }
    cur ^= 1;
  }

#pragma unroll
  for (int fi = 0; fi < 4; ++fi) {
    const int rowb = m0 + wm + fi * 16 + lg * 4;
#pragma unroll
    for (int fjp = 0; fjp < 2; ++fjp) {
      const int ucol = ((n0 + wn) >> 1) + fjp * 16 + lr;
      if (ucol >= FI_PAD) continue;
      const bool live = (ucol < FI);
      const float ba = live ? bias[ucol] : 0.0f;
      const float bg = live ? bias[FI + ucol] : 0.0f;
#pragma unroll
      for (int r = 0; r < 4; ++r) {
        const float va = acc[fi][2 * fjp][r] + ba;
        const float vg = acc[fi][2 * fjp + 1][r] + bg;
        const float gel = 0.5f * vg * (1.0f + erff(vg * 0.70710678118654752f));
        Cout[(size_t)(rowb + r) * ldc + ucol] = f2bf(live ? va * gel : 0.0f);
      }
    }
  }
}

// -------- fused RoPE(q,k) + value-residual lerp + V transpose-pack --------
__global__ __launch_bounds__(256)
void rope_v_pack(const unsigned short* __restrict__ qkv_lin,
                 const float* __restrict__ cost, const float* __restrict__ sint,
                 const float* __restrict__ gm,
                 unsigned short* __restrict__ qb, unsigned short* __restrict__ kb,
                 unsigned short* __restrict__ vres,
                 unsigned short* __restrict__ vtb, int layer) {
  __shared__ unsigned short T[64][72];
  const int nt = blockIdx.x, bh = blockIdx.y;
  const int b = bh >> 4, h = bh & 15;
  const int tid = threadIdx.x;
  // ---- RoPE on q,k (q also * DH^-0.5) ----
  {
    const int pi = tid & 31, r0 = tid >> 5;
    const float scale = 0.125f;
#pragma unroll
    for (int j = 0; j < 8; ++j) {
      const int n = nt * 64 + r0 + j * 8;
      const int nf = b * Nseq + n;
      const float c = cost[n * 32 + pi], s = sint[n * 32 + pi];
      const unsigned short* qp = &qkv_lin[(size_t)nf * 3072 + h * 64 + pi * 2];
      float q0 = bf2f(qp[0]), q1 = bf2f(qp[1]);
      alignas(4) unsigned short oq[2];
      oq[0] = f2bf((q0 * c - q1 * s) * scale);
      oq[1] = f2bf((q1 * c + q0 * s) * scale);
      *(unsigned int*)&qb[((size_t)bh * Nseq + n) * 64 + pi * 2] = *(const unsigned int*)oq;
      const unsigned short* kp = &qkv_lin[(size_t)nf * 3072 + 1024 + h * 64 + pi * 2];
      float k0 = bf2f(kp[0]), k1 = bf2f(kp[1]);
      alignas(4) unsigned short ok[2];
      ok[0] = f2bf(k0 * c - k1 * s);
      ok[1] = f2bf(k1 * c + k0 * s);
      *(unsigned int*)&kb[((size_t)bh * Nseq + n) * 64 + pi * 2] = *(const unsigned int*)ok;
    }
  }
  // ---- v lerp + transpose-pack ----
#pragma unroll
  for (int p = 0; p < 2; ++p) {
    int c = tid + p * 256;
    int nl = c >> 3, cg = (c & 7) << 3;
    int n = nt * 64 + nl, nf = b * Nseq + n;
    uint4 vv = *(const uint4*)&qkv_lin[(size_t)nf * 3072 + 2048 + h * 64 + cg];
    if (layer == 0) {
      *(uint4*)&vres[((size_t)bh * Nseq + n) * 64 + cg] = vv;
      *(uint4*)&T[nl][cg] = vv;
    } else {
      alignas(16) unsigned short ve[8]; *(uint4*)ve = vv;
      uint4 rv = *(const uint4*)&vres[((size_t)bh * Nseq + n) * 64 + cg];
      alignas(16) unsigned short re[8]; *(uint4*)re = rv;
      const float mix = gm[(size_t)nf * 32 + 16 + h];
      alignas(16) unsigned short oe[8];
#pragma unroll
      for (int j = 0; j < 8; ++j) {
        float v = bf2f(ve[j]), rr = bf2f(re[j]);
        oe[j] = f2bf(v + mix * (rr - v));
      }
      *(uint4*)&T[nl][cg] = *(const uint4*)oe;
    }
  }
  __syncthreads();
#pragma unroll
  for (int p = 0; p < 2; ++p) {
    int c = tid + p * 256;
    int d = c >> 3, ng = (c & 7) << 3;
    alignas(16) unsigned short oe[8];
#pragma unroll
    for (int j = 0; j < 8; ++j) oe[j] = T[ng + j][d];
    *(uint4*)&vtb[(size_t)bh * 65536 + (size_t)d * Nseq + nt * 64 + ng] = *(const uint4*)oe;
  }
}

// ---------------- causal flash attention + gate + head-merge ----------------
__global__ __launch_bounds__(256)
void attn_fwd(const unsigned short* __restrict__ qb,
              const unsigned short* __restrict__ kb,
              const unsigned short* __restrict__ vtb,
              const float* __restrict__ gm,
              unsigned short* __restrict__ attn_out) {
  __shared__ unsigned short Ks[2][64 * 64];   // [key][dh], swizzled
  __shared__ unsigned short Vs[2][64 * 64];   // V^T: [dh][key], swizzled
  __shared__ unsigned short Ps[4][16][72];
  const int bid = blockIdx.x;
  const int x = bid & 7, rest = bid >> 3;
  const int bh = x * 8 + (rest & 7);
  const int qt = 15 - (rest >> 3);
  const int b = bh >> 4, h = bh & 15;
  const int tid = threadIdx.x;
  const int w = tid >> 6, l = tid & 63;
  const int lr = l & 15, lg = l >> 4;
  const int q0 = qt * 64 + w * 16;
  const size_t head = (size_t)bh * Nseq * DH;
  const int lrow8 = l >> 3;
  const int colsw = ((l & 7) ^ lrow8) << 3;

  auto stageKV = [&](int buf, int kt) {
    const int kv0 = kt * 64;
#pragma unroll
    for (int i = 0; i < 2; ++i) {
      const int rb = w * 16 + i * 8;
      gl_lds16(&kb[head + (size_t)(kv0 + rb + lrow8) * DH + colsw],
               &Ks[buf][rb * 64]);
      gl_lds16(&vtb[head + (size_t)(rb + lrow8) * Nseq + kv0 + colsw],
               &Vs[buf][rb * 64]);
    }
  };

  bf16x8 aq[2];
  aq[0] = *(const bf16x8*)&qb[head + (size_t)(q0 + lr) * DH + lg * 8];
  aq[1] = *(const bf16x8*)&qb[head + (size_t)(q0 + lr) * DH + 32 + lg * 8];

  float mrow[4] = {-1e30f, -1e30f, -1e30f, -1e30f};
  float lsum[4] = {0.f, 0.f, 0.f, 0.f};
  f32x4 acco[4] = {};

  stageKV(0, 0);
  asm volatile("s_waitcnt vmcnt(0)" ::: "memory");
  __builtin_amdgcn_s_barrier();
  fence_mem();

#pragma unroll 1
  for (int kt = 0; kt <= qt; ++kt) {
    const int p = kt & 1;
    const int kv0 = kt * 64;
    const bool more = (kt < qt);
    if (more) stageKV(p ^ 1, kt + 1);      // async prefetch next K/V tile
    f32x4 s[4];
#pragma unroll
    for (int t = 0; t < 4; ++t) {
      const int krow = t * 16 + lr;
      bf16x8 bk0 = *(const bf16x8*)&Ks[p][krow * 64 + ((0 + lg) ^ (lr & 7)) * 8];
      bf16x8 bk1 = *(const bf16x8*)&Ks[p][krow * 64 + ((4 + lg) ^ (lr & 7)) * 8];
      f32x4 z = {};
      z = __builtin_amdgcn_mfma_f32_16x16x32_bf16(aq[0], bk0, z, 0, 0, 0);
      z = __builtin_amdgcn_mfma_f32_16x16x32_bf16(aq[1], bk1, z, 0, 0, 0);
      s[t] = z;
    }
    const bool diag = (kt == qt);
    float mx4[4];
    bool need = false;
#pragma unroll
    for (int r = 0; r < 4; ++r) {
      const int qr = q0 + lg * 4 + r;
      float mx = -1e30f;
#pragma unroll
      for (int t = 0; t < 4; ++t) {
        float sv = s[t][r];
        if (diag && (kv0 + t * 16 + lr > qr)) sv = -1e30f;
        s[t][r] = sv;
        mx = fmaxf(mx, sv);
      }
      mx = fmaxf(mx, __shfl_xor(mx, 1, 64));
      mx = fmaxf(mx, __shfl_xor(mx, 2, 64));
      mx = fmaxf(mx, __shfl_xor(mx, 4, 64));
      mx = fmaxf(mx, __shfl_xor(mx, 8, 64));
      mx4[r] = mx;
      need = need || (mx > mrow[r] + 8.0f);
    }
    if (__any(need)) {    // defer-max
#pragma unroll
      for (int r = 0; r < 4; ++r) {
        const float mn = fmaxf(mrow[r], mx4[r]);
        const float alpha = __expf(mrow[r] - mn);
        mrow[r] = mn;
        lsum[r] *= alpha;
#pragma unroll
        for (int dt = 0; dt < 4; ++dt) acco[dt][r] *= alpha;
      }
    }
#pragma unroll
    for (int r = 0; r < 4; ++r) {
      float rs = 0.f;
#pragma unroll
      for (int t = 0; t < 4; ++t) {
        float pv = __expf(s[t][r] - mrow[r]);   // bounded by e^8
        s[t][r] = pv;
        rs += pv;
      }
      rs += __shfl_xor(rs, 1, 64);
      rs += __shfl_xor(rs, 2, 64);
      rs += __shfl_xor(rs, 4, 64);
      rs += __shfl_xor(rs, 8, 64);
      lsum[r] += rs;
    }
#pragma unroll
    for (int t = 0; t < 4; ++t)
#pragma unroll
      for (int r = 0; r < 4; ++r)
        Ps[w][lg * 4 + r][t * 16 + lr] = f2bf(s[t][r]);
#pragma unroll
    for (int ks = 0; ks < 2; ++ks) {
      bf16x8 ap = *(const bf16x8*)&Ps[w][lr][ks * 32 + lg * 8];
#pragma unroll
      for (int dt = 0; dt < 4; ++dt) {
        const int vrow = dt * 16 + lr;
        bf16x8 bv = *(const bf16x8*)&Vs[p][vrow * 64 + ((ks * 4 + lg) ^ (lr & 7)) * 8];
        acco[dt] = __builtin_amdgcn_mfma_f32_16x16x32_bf16(ap, bv, acco[dt], 0, 0, 0);
      }
    }
    if (more) {
      asm volatile("s_waitcnt vmcnt(0)" ::: "memory");  // next tile landed
      __builtin_amdgcn_s_barrier();                     // all waves done with buf p
      fence_mem();
    }
  }

#pragma unroll
  for (int r = 0; r < 4; ++r) {
    const int qr = q0 + lg * 4 + r;
    const int nf = b * Nseq + qr;
    const float gate = gm[(size_t)nf * 32 + h];
    const float inv = 1.0f / lsum[r];
#pragma unroll
    for (int dt = 0; dt < 4; ++dt)
      attn_out[(size_t)nf * Dm + h * DH + dt * 16 + lr] = f2bf(acco[dt][r] * inv * gate);
  }
}

// ---------------- host launch ----------------
extern "C" void kernel_launch(void* const* d_in, const int* in_sizes, int n_in,
                              void* d_out, int out_size, void* d_ws, size_t ws_size,
                              hipStream_t stream) {
  const float* x_in  = (const float*)d_in[0];
  const float* naw   = (const float*)d_in[1];
  const float* wq    = (const float*)d_in[2];
  const float* wkv   = (const float*)d_in[3];
  const float* wo    = (const float*)d_in[4];
  const float* wg    = (const float*)d_in[5];
  const float* wmix  = (const float*)d_in[6];
  const float* nfw   = (const float*)d_in[7];
  const float* ffw   = (const float*)d_in[8];
  const float* w_in  = (const float*)d_in[9];
  const float* b_in  = (const float*)d_in[10];
  const float* w_out = (const float*)d_in[11];
  const float* b_out = (const float*)d_in[12];
  const float* fnw   = (const float*)d_in[13];

  uint8_t* ws = (uint8_t*)d_ws;
  size_t off = 0;
  auto alloc = [&](size_t bytes) -> void* {
    void* p = ws + off;
    off += (bytes + 255) & ~(size_t)255;
    return p;
  };
  float*          x_res    = (float*)alloc((size_t)ROWS * Dm * 4);
  unsigned short* h        = (unsigned short*)alloc((size_t)ROWS * Dm * 2);
  unsigned short* qkv_lin  = (unsigned short*)alloc((size_t)ROWS * 3072 * 2);
  float*          gm       = (float*)alloc((size_t)ROWS * 32 * 4);
  unsigned short* qb       = (unsigned short*)alloc((size_t)64 * Nseq * DH * 2);
  unsigned short* kb       = (unsigned short*)alloc((size_t)64 * Nseq * DH * 2);
  unsigned short* vtb      = (unsigned short*)alloc((size_t)64 * Nseq * DH * 2);
  unsigned short* vres     = (unsigned short*)alloc((size_t)64 * Nseq * DH * 2);
  unsigned short* attn     = (unsigned short*)alloc((size_t)ROWS * Dm * 2);
  float*          cost     = (float*)alloc((size_t)Nseq * 32 * 4);
  float*          sint     = (float*)alloc((size_t)Nseq * 32 * 4);
  // per-layer weight buffers (x4 layers, layer-strided)
  unsigned short* wqkv_bf  = (unsigned short*)alloc((size_t)NDEPTH * 3072 * 1024 * 2);
  unsigned short* wo_bf    = (unsigned short*)alloc((size_t)NDEPTH * 1024 * 1024 * 2);
  unsigned short* wgm_bf   = (unsigned short*)alloc((size_t)NDEPTH * 128 * 1024 * 2);
  unsigned short* win_bf   = (unsigned short*)alloc((size_t)NDEPTH * WIDE * 1024 * 2);
  unsigned short* wout_bf  = (unsigned short*)alloc((size_t)NDEPTH * 1024 * FI_PAD * 2);
  unsigned short* u = qkv_lin;  // alias: qkv scratch dead before FF uses u

  hipMemcpyAsync(x_res, x_in, (size_t)ROWS * Dm * 4, hipMemcpyDeviceToDevice, stream);
  rope_tables<<<128, 256, 0, stream>>>(cost, sint);

  // ---- all-layer weight conversion (8 dispatches total) ----
  constexpr size_t QS = (size_t)3072 * 1024;   // wqkv dst layer stride
  convf2b<<<dim3(1, 1024, NDEPTH), 128, 0, stream>>>(wq, wqkv_bf, 1024, 1024, 1024,
                                                     (size_t)1024 * 1024, QS);
  convf2b<<<dim3(1, 2048, NDEPTH), 128, 0, stream>>>(wkv, wqkv_bf + (size_t)1024 * 1024, 2048, 1024, 1024,
                                                     (size_t)2048 * 1024, QS);
  convf2b<<<dim3(1, 1024, NDEPTH), 128, 0, stream>>>(wo, wo_bf, 1024, 1024, 1024,
                                                     (size_t)1024 * 1024, (size_t)1024 * 1024);
  convf2b<<<dim3(1, 16, NDEPTH), 128, 0, stream>>>(wg, wgm_bf, 16, 1024, 1024,
                                                   (size_t)16 * 1024, (size_t)128 * 1024);
  convf2b<<<dim3(1, 16, NDEPTH), 128, 0, stream>>>(wmix, wgm_bf + 16 * 1024, 16, 1024, 1024,
                                                   (size_t)16 * 1024, (size_t)128 * 1024);
  convf2b<<<dim3(1, 96, NDEPTH), 128, 0, stream>>>(wg, wgm_bf + 32 * 1024, 0, 1024, 1024,
                                                   0, (size_t)128 * 1024);
  convf2b_g16<<<dim3(1, WIDE, NDEPTH), 128, 0, stream>>>(w_in, win_bf);
  convf2b<<<dim3(2, 1024, NDEPTH), 256, 0, stream>>>(w_out, wout_bf, 1024, FI, FI_PAD,
                                                     (size_t)1024 * FI, (size_t)1024 * FI_PAD);

  for (int i = 0; i < NDEPTH; ++i) {
    unsigned short* wqkv_i = wqkv_bf + (size_t)i * 3072 * 1024;
    unsigned short* wo_i   = wo_bf   + (size_t)i * 1024 * 1024;
    unsigned short* wgm_i  = wgm_bf  + (size_t)i * 128 * 1024;
    unsigned short* win_i  = win_bf  + (size_t)i * WIDE * 1024;
    unsigned short* wout_i = wout_bf + (size_t)i * 1024 * FI_PAD;

    rms_one<<<ROWS, 256, 0, stream>>>(x_res, naw + i * 1024, h);
    gemm_nt256<0><<<192, 512, 0, stream>>>(h, wqkv_i, qkv_lin, nullptr, 1024, 3072, 16, 12);
    gemm_nt<1><<<dim3(32, 1), 256, 0, stream>>>(h, wgm_i, gm, nullptr, nullptr, 1024, 32, 32);
    rope_v_pack<<<dim3(16, 64), 256, 0, stream>>>(qkv_lin, cost, sint, gm, qb, kb, vres, vtb, i);
    attn_fwd<<<1024, 256, 0, stream>>>(qb, kb, vtb, gm, attn);
    gemm_nt<2><<<dim3(32, 8), 256, 0, stream>>>(attn, wo_i, x_res, nullptr, x_res, 1024, 1024, 1024);
    rms_ff<<<ROWS, 256, 0, stream>>>(x_res, nfw + i * 1024, ffw + i * 1024, h);
    gemm_geglu128<<<704, 512, 0, stream>>>(h, win_i, u, b_in + (size_t)i * 2 * FI, 1024, FI_PAD, 32, 22);
    gemm_nt<2><<<dim3(32, 8), 256, 0, stream>>>(u, wout_bf + (size_t)i * 1024 * FI_PAD, x_res, b_out + i * 1024, x_res, FI_PAD, 1024, 1024);
    (void)wout_i;
  }
  rms_final<<<ROWS, 256, 0, stream>>>(x_res, fnw, (float*)d_out);
}